// Round 4
// baseline (98.407 us; speedup 1.0000x reference)
//
#include <hip/hip_runtime.h>
#include <stdint.h>

// AAF loss, round 17: scalarized stage-2 via T/SL precompute + symmetric
// re-pairing.
// Stage-1 stores per pixel: packed f16 a-row (clip p) and l-row (log2 clip
// (1-p)) [80 B, stride 20 words], plus TL = (lab<<16 | f16(T)) where
// T = sum_c (a*d + l). Own regs keep d,l pairs + scalars SL, u=t[lab],
// v=a[lab], dlab, llab.
// Stage-2 per neighbor: dot = T_N - fdot(a_N, d_own) - SL (10 fdot2, no kl
// materialization). kl@lab_P for BOTH ordered pairs (P,N) and (N,P) from 2
// LDS words at own-label offset + one shared log2; the @lab_N terms arrive
// symmetrically from the neighbor (weighted swe/swn[nlab]). Exact
// re-partition of the original sums.
// Paths: deep blocks (bx,by in [2,29]) pure re-paired; ring-1 interior
// blocks per-neighbor E check (neighbor in interior block?) with
// self-contained fallback; border blocks fully self-contained incl. pads
// (pad ekall from own regs + constants) and reverse-ignore gates.

#define NC 19
#define HH 512
#define WW 512
#define NB 2
#define TS 16
#define HS 18                          // TS + 2 halo
#define HP (HS * HS)                   // 324
#define ATRS 20                        // words: a-pairs 0..9, l-pairs 10..19
#define PS 25                          // 5x5 source patch per class
#define NBLK 2048
#define LOG2E 1.4426950408889634f
#define LN2 0.6931471805599453f
#define LOG2EPS -13.287712379549449f   // log2(1e-4)
#define K2F 4.3280851226668906f        // 3/ln2: KLD margin in log2 units
#define K2PAD 4.328125f                // (_Float16)K2F exactly (pad-slot value)

typedef _Float16 f16x2 __attribute__((ext_vector_type(2)));

#if __has_builtin(__builtin_amdgcn_exp2f)
#define EXP2F(x) __builtin_amdgcn_exp2f(x)
#else
#define EXP2F(x) __expf((x) * LN2)
#endif

#if __has_builtin(__builtin_amdgcn_fdot2)
#define FDOT2(a, b, c) __builtin_amdgcn_fdot2((a), (b), (c), false)
#else
#define FDOT2(a, b, c) fmaf((float)(a)[1], (float)(b)[1], fmaf((float)(a)[0], (float)(b)[0], (c)))
#endif

struct Part { float es, ns; unsigned int cnt, pad; };
struct Own { float SL, u, v, dlab, llab; };

union U32F2 { uint32_t u; f16x2 h; };
__device__ __forceinline__ uint32_t bc_u32(f16x2 v) { U32F2 x; x.h = v; return x.u; }
__device__ __forceinline__ f16x2 bc_h2(uint32_t v) { U32F2 x; x.u = v; return x.h; }
__device__ __forceinline__ float extf(f16x2 v, int h) { return h ? (float)v[1] : (float)v[0]; }

union U16H { uint16_t u; _Float16 h; };
__device__ __forceinline__ uint32_t pack_TL(int lab, float T) {
    U16H t; t.h = (_Float16)T;
    return ((uint32_t)lab << 16) | (uint32_t)t.u;
}
__device__ __forceinline__ float TL_T(uint32_t tl) {
    U16H t; t.u = (uint16_t)(tl & 0xFFFFu);
    return (float)t.h;
}

// One pixel's softmax -> a-row (words 0..9) + l-row (words 10..19) + TL.
// All log2 domain. KEEP: d,l pairs kept in regs + Own scalars.
// Returns label (255 = OOB pad).
template <bool KEEP>
__device__ __forceinline__ int pix_compute(const float* __restrict__ patch,
                                           const int* __restrict__ tg,
                                           int y, int x, int y0b, int x0b,
                                           uint32_t* __restrict__ ATrow,
                                           uint32_t* __restrict__ TLw,
                                           f16x2* Dh, f16x2* Lh, Own* os) {
    const bool oob = ((unsigned)y >= (unsigned)HH) | ((unsigned)x >= (unsigned)WW);
    if (oob) {
        const _Float16 aP = (_Float16)1e-4f;
        const uint32_t aPP = bc_u32((f16x2){aP, aP});
        const uint32_t aPL = bc_u32((f16x2){aP, (_Float16)0.0f});
        uint4 W0, W1, W2, W3, W4;
        W0.x = aPP; W0.y = aPP; W0.z = aPP; W0.w = aPP;       // a pairs 0-3
        W1 = W0;                                               // a pairs 4-7
        W2.x = aPP; W2.y = aPL; W2.z = 0u; W2.w = 0u;          // a8, a9, l0, l1
        W3.x = 0u; W3.y = 0u; W3.z = 0u; W3.w = 0u;            // l2-l5
        W4 = W3;                                               // l6-l9
        *reinterpret_cast<uint4*>(ATrow + 0)  = W0;
        *reinterpret_cast<uint4*>(ATrow + 4)  = W1;
        *reinterpret_cast<uint4*>(ATrow + 8)  = W2;
        *reinterpret_cast<uint4*>(ATrow + 12) = W3;
        *reinterpret_cast<uint4*>(ATrow + 16) = W4;
        *TLw = pack_TL(255, 0.0f);
        if (KEEP) {
            const _Float16 dP = (_Float16)LOG2EPS;
#pragma unroll
            for (int j = 0; j < 10; ++j) {
                Dh[j] = (j < 9) ? (f16x2){dP, dP} : (f16x2){dP, (_Float16)0.0f};
                Lh[j] = (f16x2){(_Float16)0.0f, (_Float16)0.0f};
            }
            os->SL = 0.0f; os->u = 0.0f; os->v = 0.0f; os->dlab = 0.0f; os->llab = 0.0f;
        }
        return 255;
    }

    const int lab = tg[(y << 9) + x];
    const float fy = (float)(y * 63) / 511.0f;
    const float fx = (float)(x * 63) / 511.0f;
    const int y0 = (int)fy, x0 = (int)fx;
    const float wy = fy - (float)y0, wx = fx - (float)x0;
    const int y1 = min(y0 + 1, 63), x1 = min(x0 + 1, 63);
    const float omwy = 1.0f - wy, omwx = 1.0f - wx;
    const float w00 = omwy * omwx, w01 = omwy * wx;
    const float w10 = wy * omwx,   w11 = wy * wx;
    const int o00 = (y0 - y0b) * 5 + (x0 - x0b);
    const int o01 = o00 + (x1 - x0);
    const int o10 = o00 + (y1 - y0) * 5;
    const int o11 = o10 + (x1 - x0);

    float v2[NC], w[NC];
    float s = 0.0f;
#pragma unroll
    for (int c = 0; c < NC; ++c) {
        const float* pc_ = &patch[c * PS];
        const float vv = fmaf(pc_[o00], w00, fmaf(pc_[o01], w01,
                          fmaf(pc_[o10], w10, pc_[o11] * w11)));
        v2[c] = vv;
        const float e = EXP2F(vv);
        w[c] = e;
        s += e;
    }
    const float inv = 1.0f / s;
    const float lns2 = __log2f(s);            // log2 p = v2 - lns2

    float Tdd = 0.0f, SL = 0.0f;
    uint32_t aw_[10], lw_[10];
#pragma unroll
    for (int j = 0; j < 10; ++j) {
        _Float16 a0 = (_Float16)0.0f, l0 = (_Float16)0.0f, d0 = (_Float16)0.0f;
        _Float16 a1 = (_Float16)0.0f, l1 = (_Float16)0.0f, d1 = (_Float16)0.0f;
        {
            const int c = 2 * j;
            const float p = w[c] * inv;
            const float la = fmaxf(v2[c] - lns2, LOG2EPS);
            const float aa = fmaxf(p, 1e-4f);
            const float lb = __log2f(fmaxf(1.0f - p, 1e-4f));
            const float dd = la - lb;
            Tdd = fmaf(aa, dd, Tdd); SL += lb;
            a0 = (_Float16)aa; l0 = (_Float16)lb; d0 = (_Float16)dd;
        }
        if (2 * j + 1 < NC) {
            const int c = 2 * j + 1;
            const float p = w[c] * inv;
            const float la = fmaxf(v2[c] - lns2, LOG2EPS);
            const float aa = fmaxf(p, 1e-4f);
            const float lb = __log2f(fmaxf(1.0f - p, 1e-4f));
            const float dd = la - lb;
            Tdd = fmaf(aa, dd, Tdd); SL += lb;
            a1 = (_Float16)aa; l1 = (_Float16)lb; d1 = (_Float16)dd;
        }
        aw_[j] = bc_u32((f16x2){a0, a1});
        lw_[j] = bc_u32((f16x2){l0, l1});
        if (KEEP) { Dh[j] = (f16x2){d0, d1}; Lh[j] = (f16x2){l0, l1}; }
    }
    {
        uint4 W0, W1, W2, W3, W4;
        W0.x = aw_[0]; W0.y = aw_[1]; W0.z = aw_[2]; W0.w = aw_[3];
        W1.x = aw_[4]; W1.y = aw_[5]; W1.z = aw_[6]; W1.w = aw_[7];
        W2.x = aw_[8]; W2.y = aw_[9]; W2.z = lw_[0]; W2.w = lw_[1];
        W3.x = lw_[2]; W3.y = lw_[3]; W3.z = lw_[4]; W3.w = lw_[5];
        W4.x = lw_[6]; W4.y = lw_[7]; W4.z = lw_[8]; W4.w = lw_[9];
        *reinterpret_cast<uint4*>(ATrow + 0)  = W0;
        *reinterpret_cast<uint4*>(ATrow + 4)  = W1;
        *reinterpret_cast<uint4*>(ATrow + 8)  = W2;
        *reinterpret_cast<uint4*>(ATrow + 12) = W3;
        *reinterpret_cast<uint4*>(ATrow + 16) = W4;
    }
    *TLw = pack_TL(lab, Tdd + SL);

    if (KEEP) {
        // recompute own-label scalars directly (no runtime reg indexing)
        const float* pl = &patch[lab * PS];
        const float vlab = fmaf(pl[o00], w00, fmaf(pl[o01], w01,
                            fmaf(pl[o10], w10, pl[o11] * w11)));
        const float p = EXP2F(vlab) * inv;
        const float la = fmaxf(vlab - lns2, LOG2EPS);
        const float aa = fmaxf(p, 1e-4f);
        const float lb = __log2f(fmaxf(1.0f - p, 1e-4f));
        const float dd = la - lb;
        os->SL = SL;
        os->dlab = dd;
        os->llab = lb;
        os->u = fmaf(aa, dd, lb);
        os->v = aa;
    }
    return lab;
}

__global__ __launch_bounds__(256, 5) void k_fused(const float* __restrict__ preds,
                                                  const int* __restrict__ targets,
                                                  const float* __restrict__ w_edge,
                                                  const float* __restrict__ w_not_edge,
                                                  Part* __restrict__ pb) {
    __shared__ __align__(16) uint32_t AT[HP * ATRS];  // 25,920 B
    __shared__ uint32_t TL[HP];                       // 1,296 B (lab<<16 | f16 T)
    __shared__ float2 swen[NC];                       // (swe, swn), ln2-folded
    __shared__ float patch[NC * PS];
    __shared__ float r_es[4], r_ns[4];
    __shared__ unsigned int r_cnt[4];

    const int tid = threadIdx.x;
    const int bx = blockIdx.x, by = blockIdx.y, n = blockIdx.z;

    if (tid < NC) {
        float sw_e, sw_n;
        {
            float a = w_edge[tid * 3 + 0], b = w_edge[tid * 3 + 1], c = w_edge[tid * 3 + 2];
            float m = fmaxf(a, fmaxf(b, c));
            float ea = __expf(a - m), eb = __expf(b - m), ec = __expf(c - m);
            sw_e = (ea / (ea + eb + ec)) * LN2;
        }
        {
            float a = w_not_edge[tid * 3 + 0], b = w_not_edge[tid * 3 + 1], c = w_not_edge[tid * 3 + 2];
            float m = fmaxf(a, fmaxf(b, c));
            float ea = __expf(a - m), eb = __expf(b - m), ec = __expf(c - m);
            sw_n = (ea / (ea + eb + ec)) * LN2;
        }
        swen[tid] = make_float2(sw_e, sw_n);
    }

    const int* tg = targets + (n << 18);
    const float* pbase = preds + (size_t)n * NC * 4096;

    const int ty = tid >> 4, tx = tid & 15;
    const int hi = (ty + 1) * HS + (tx + 1);
    const int DOFF[8] = {-HS - 1, -HS, -HS + 1, -1, 1, HS - 1, HS, HS + 1};
    const int DY[8] = {-1, -1, -1, 0, 0, 1, 1, 1};
    const int DX[8] = {-1, 0, 1, -1, 1, -1, 0, 1};
    const f16x2 one2 = {(_Float16)1.0f, (_Float16)1.0f};
    const f16x2 k32 = {(_Float16)K2F, (_Float16)K2F};

    float e_s = 0.0f, ne_s = 0.0f;
    unsigned int cnt = 0;               // e_c << 16 | ne_c

    // ---- stage 0: stage 5x5x19 source patch, pre-scaled by log2e ----
    const int yT = max(by * TS - 1, 0), xL = max(bx * TS - 1, 0);
    const int y0b = (yT * 63) / 511, x0b = (xL * 63) / 511;
    for (int t = tid; t < NC * PS; t += 256) {
        const int c = t / PS, r = t - c * PS;
        const int ry = r / 5, rx = r - ry * 5;
        const int sy = min(y0b + ry, 63), sx = min(x0b + rx, 63);
        patch[t] = pbase[c * 4096 + (sy << 6) + sx] * LOG2E;
    }
    __syncthreads();

    // ---- stage 1: halo ring first (temps die), then own pixel ----
    if (tid < 68) {
        int i;
        if (tid < 18)      i = tid;                       // top row
        else if (tid < 36) i = 306 + (tid - 18);          // bottom row
        else if (tid < 52) i = (tid - 35) * HS;           // left col (rows 1..16)
        else               i = (tid - 51) * HS + 17;      // right col (rows 1..16)
        const int hy = i / HS, hx = i - hy * HS;
        pix_compute<false>(patch, tg, by * TS + hy - 1, bx * TS + hx - 1,
                           y0b, x0b, &AT[i * ATRS], &TL[i], nullptr, nullptr, nullptr);
    }

    f16x2 Dh[10], Lh[10];
    Own os;
    const int lab = pix_compute<true>(patch, tg, by * TS + ty, bx * TS + tx,
                                      y0b, x0b, &AT[hi * ATRS], &TL[hi], Dh, Lh, &os);
    __syncthreads();

    // ---- stage 2 ----
    const bool interior_blk = (bx > 0) & (bx < 31) & (by > 0) & (by < 31);
    const bool deep_blk = (bx > 1) & (bx < 30) & (by > 1) & (by < 30);
    const int plab = lab >> 1, hlab = lab & 1;
    const float SL = os.SL, u = os.u, v = os.v, dlab = os.dlab, llab = os.llab;
    const uint32_t* myrow = &AT[hi * ATRS];
    float es_o = 0.0f, ns_o = 0.0f;     // owner-weighted (x swen[lab] at end)
    float es_w = 0.0f, ns_w = 0.0f;     // pre-weighted reverse contributions

    if (deep_blk) {
#pragma unroll
        for (int k = 0; k < 8; ++k) {
            const int np = hi + DOFF[k];
            const uint32_t tl = TL[np];
            const int nlab = (int)(tl >> 16);
            const float T_N = TL_T(tl);
            const uint32_t* rb = &AT[np * ATRS];
            const uint4 A0 = *reinterpret_cast<const uint4*>(rb);
            const uint4 A1 = *reinterpret_cast<const uint4*>(rb + 4);
            const uint2 A2 = *reinterpret_cast<const uint2*>(rb + 8);
            float acc = 0.0f;
            acc = FDOT2(bc_h2(A0.x), Dh[0], acc);
            acc = FDOT2(bc_h2(A0.y), Dh[1], acc);
            acc = FDOT2(bc_h2(A0.z), Dh[2], acc);
            acc = FDOT2(bc_h2(A0.w), Dh[3], acc);
            acc = FDOT2(bc_h2(A1.x), Dh[4], acc);
            acc = FDOT2(bc_h2(A1.y), Dh[5], acc);
            acc = FDOT2(bc_h2(A1.z), Dh[6], acc);
            acc = FDOT2(bc_h2(A1.w), Dh[7], acc);
            acc = FDOT2(bc_h2(A2.x), Dh[8], acc);
            acc = FDOT2(bc_h2(A2.y), Dh[9], acc);
            const float dot = T_N - acc - SL;
            const float aN = extf(bc_h2(rb[plab]), hlab);      // a_N[lab]
            const float lN = extf(bc_h2(rb[10 + plab]), hlab); // l_N[lab]
            const float dN = __log2f(aN) - lN;
            const float klL = fmaf(aN, dN, lN) - fmaf(aN, dlab, llab); // kl(P,N)@labP
            const float klR = u - fmaf(v, dN, lN);                      // kl(N,P)@labP
            const bool df = (lab != nlab);
            const float wg = df ? 1.0f : 0.0f;
            const float2 sw = swen[nlab];
            es_o = fmaf(wg, fmaxf(K2F - klL, 0.0f), es_o);
            ns_o += dot - wg * klL;
            es_w = fmaf(wg * sw.x, fmaxf(K2F - klR, 0.0f), es_w);
            ns_w = fmaf(-wg * sw.y, klR, ns_w);
            cnt += df ? ((2u << 16) | (NC - 2)) : NC;
        }
    } else if (interior_blk) {
        const int gy = by * TS + ty, gx = bx * TS + tx;
#pragma unroll
        for (int k = 0; k < 8; ++k) {
            const int np = hi + DOFF[k];
            const uint32_t tl = TL[np];
            const int nlab = (int)(tl >> 16);
            const float T_N = TL_T(tl);
            const uint32_t* rb = &AT[np * ATRS];
            const uint4 A0 = *reinterpret_cast<const uint4*>(rb);
            const uint4 A1 = *reinterpret_cast<const uint4*>(rb + 4);
            const uint2 A2 = *reinterpret_cast<const uint2*>(rb + 8);
            float acc = 0.0f;
            acc = FDOT2(bc_h2(A0.x), Dh[0], acc);
            acc = FDOT2(bc_h2(A0.y), Dh[1], acc);
            acc = FDOT2(bc_h2(A0.z), Dh[2], acc);
            acc = FDOT2(bc_h2(A0.w), Dh[3], acc);
            acc = FDOT2(bc_h2(A1.x), Dh[4], acc);
            acc = FDOT2(bc_h2(A1.y), Dh[5], acc);
            acc = FDOT2(bc_h2(A1.z), Dh[6], acc);
            acc = FDOT2(bc_h2(A1.w), Dh[7], acc);
            acc = FDOT2(bc_h2(A2.x), Dh[8], acc);
            acc = FDOT2(bc_h2(A2.y), Dh[9], acc);
            const float dot = T_N - acc - SL;
            const float aN = extf(bc_h2(rb[plab]), hlab);
            const float lN = extf(bc_h2(rb[10 + plab]), hlab);
            const float dN = __log2f(aN) - lN;
            const float klL = fmaf(aN, dN, lN) - fmaf(aN, dlab, llab);
            const bool df = (lab != nlab);
            const float wg = df ? 1.0f : 0.0f;
            const int gyN = gy + DY[k], gxN = gx + DX[k];
            const bool E = ((unsigned)(gyN - 16) < 480u) & ((unsigned)(gxN - 16) < 480u);
            if (E) {
                const float klR = u - fmaf(v, dN, lN);
                const float2 sw = swen[nlab];
                es_o = fmaf(wg, fmaxf(K2F - klL, 0.0f), es_o);
                ns_o += dot - wg * klL;
                es_w = fmaf(wg * sw.x, fmaxf(K2F - klR, 0.0f), es_w);
                ns_w = fmaf(-wg * sw.y, klR, ns_w);
            } else {
                // self-contained: neighbor in border block (in-image, no pad)
                const int pn = nlab >> 1, hn = nlab & 1;
                const float aN2 = extf(bc_h2(rb[pn]), hn);        // a_N[nlab]
                const float lN2 = extf(bc_h2(rb[10 + pn]), hn);   // l_N[nlab]
                const float dN2 = __log2f(aN2) - lN2;
                const float ao = extf(bc_h2(myrow[pn]), hn);      // a_own[nlab]
                const float lo = extf(bc_h2(myrow[10 + pn]), hn); // l_own[nlab]
                const float doo = __log2f(ao) - lo;
                const float klN = fmaf(aN2, dN2, lN2) - fmaf(aN2, doo, lo);
                es_o = fmaf(wg, fmaxf(K2F - klL, 0.0f) + fmaxf(K2F - klN, 0.0f), es_o);
                ns_o += dot - wg * (klL + klN);
            }
            cnt += df ? ((2u << 16) | (NC - 2)) : NC;
        }
    } else if (lab <= NC - 1) {
        // ---- border path: self-contained, pads + reverse-ignore gates ----
        const _Float16 aP = (_Float16)1e-4f, dP = (_Float16)LOG2EPS;
        const _Float16 tP = (_Float16)((float)aP * (float)dP);
        const f16x2 ap2 = {aP, aP}, ap2L = {aP, (_Float16)0.0f};
        const f16x2 tp2 = {tP, tP}, tp2L = {tP, (_Float16)0.0f};
#pragma unroll
        for (int k = 0; k < 8; ++k) {
            const int off = DOFF[k];
            const int rlab = (int)(TL[hi - off] >> 16);
            const bool rvalid = (rlab <= NC - 1);
            const int np = hi + off;
            const uint32_t tl = TL[np];
            const int nlab = (int)(tl >> 16);
            const bool isPad = (nlab == 255);
            float ek_k, nk_k;
            unsigned int pc;
            if (isPad) {
                float ekall = 0.0f;
#pragma unroll
                for (int j = 0; j < 10; ++j) {
                    const f16x2 a2 = (j < 9) ? ap2 : ap2L;
                    const f16x2 t2 = (j < 9) ? tp2 : tp2L;
                    f16x2 kl = t2 - (a2 * Dh[j] + Lh[j]);
                    f16x2 m = k32 - kl;
                    m[0] = m[0] > (_Float16)0.0f ? m[0] : (_Float16)0.0f;
                    m[1] = m[1] > (_Float16)0.0f ? m[1] : (_Float16)0.0f;
                    ekall = FDOT2(m, one2, ekall);
                }
                ek_k = ekall - K2PAD;   // drop zero-pad slot (kl=0 -> K2)
                nk_k = 0.0f;
                pc = NC;
            } else {
                const float T_N = TL_T(tl);
                const uint32_t* rb = &AT[np * ATRS];
                const uint4 A0 = *reinterpret_cast<const uint4*>(rb);
                const uint4 A1 = *reinterpret_cast<const uint4*>(rb + 4);
                const uint2 A2 = *reinterpret_cast<const uint2*>(rb + 8);
                float acc = 0.0f;
                acc = FDOT2(bc_h2(A0.x), Dh[0], acc);
                acc = FDOT2(bc_h2(A0.y), Dh[1], acc);
                acc = FDOT2(bc_h2(A0.z), Dh[2], acc);
                acc = FDOT2(bc_h2(A0.w), Dh[3], acc);
                acc = FDOT2(bc_h2(A1.x), Dh[4], acc);
                acc = FDOT2(bc_h2(A1.y), Dh[5], acc);
                acc = FDOT2(bc_h2(A1.z), Dh[6], acc);
                acc = FDOT2(bc_h2(A1.w), Dh[7], acc);
                acc = FDOT2(bc_h2(A2.x), Dh[8], acc);
                acc = FDOT2(bc_h2(A2.y), Dh[9], acc);
                const float dot = T_N - acc - SL;
                const float aN = extf(bc_h2(rb[plab]), hlab);
                const float lN = extf(bc_h2(rb[10 + plab]), hlab);
                const float dN = __log2f(aN) - lN;
                const float klL = fmaf(aN, dN, lN) - fmaf(aN, dlab, llab);
                const int pn = nlab >> 1, hn = nlab & 1;
                const float aN2 = extf(bc_h2(rb[pn]), hn);
                const float lN2 = extf(bc_h2(rb[10 + pn]), hn);
                const float dN2 = __log2f(aN2) - lN2;
                const float ao = extf(bc_h2(myrow[pn]), hn);
                const float lo = extf(bc_h2(myrow[10 + pn]), hn);
                const float doo = __log2f(ao) - lo;
                const float klN = fmaf(aN2, dN2, lN2) - fmaf(aN2, doo, lo);
                const bool df = (lab != nlab);
                const float wg = df ? 1.0f : 0.0f;
                ek_k = wg * (fmaxf(K2F - klL, 0.0f) + fmaxf(K2F - klN, 0.0f));
                nk_k = dot - wg * (klL + klN);
                pc = df ? 2u : 0u;
            }
            const float vf = rvalid ? 1.0f : 0.0f;
            es_o = fmaf(vf, ek_k, es_o);
            ns_o = fmaf(vf, nk_k, ns_o);
            cnt += rvalid ? ((pc << 16) | (NC - pc)) : 0u;
        }
    }

    {
        const float2 swl = swen[lab <= NC - 1 ? lab : 0];
        e_s  = fmaf(es_o, swl.x, es_w);
        ne_s = fmaf(ns_o, swl.y, ns_w);
    }

    // ---- block reduction ----
#pragma unroll
    for (int off = 32; off > 0; off >>= 1) {
        e_s  += __shfl_down(e_s, off, 64);
        ne_s += __shfl_down(ne_s, off, 64);
        cnt  += __shfl_down(cnt, off, 64);
    }
    const int wid = tid >> 6, lane = tid & 63;
    if (lane == 0) { r_es[wid] = e_s; r_ns[wid] = ne_s; r_cnt[wid] = cnt; }
    __syncthreads();
    if (tid == 0) {
        float tes = 0.0f, tns = 0.0f;
        unsigned int tc = 0;
#pragma unroll
        for (int w = 0; w < 4; ++w) { tes += r_es[w]; tns += r_ns[w]; tc += r_cnt[w]; }
        const int bid = (blockIdx.z * gridDim.y + blockIdx.y) * gridDim.x + blockIdx.x;
        pb[bid].es = tes; pb[bid].ns = tns; pb[bid].cnt = tc; pb[bid].pad = 0;
    }
}

// ---------------- final reduce (1 block) ----------------
__global__ __launch_bounds__(256) void k_final(const Part* __restrict__ pb,
                                               float* __restrict__ out) {
    const int tid = threadIdx.x;
    double es = 0.0, ns = 0.0;
    long long ec = 0, nc = 0;
    for (int i = tid; i < NBLK; i += 256) {
        es += (double)pb[i].es; ns += (double)pb[i].ns;
        const unsigned int c = pb[i].cnt;
        ec += (long long)(c >> 16); nc += (long long)(c & 0xFFFFu);
    }
#pragma unroll
    for (int off = 32; off > 0; off >>= 1) {
        es += __shfl_down(es, off, 64);
        ns += __shfl_down(ns, off, 64);
        ec += __shfl_down(ec, off, 64);
        nc += __shfl_down(nc, off, 64);
    }
    __shared__ double ses[4], sns[4];
    __shared__ long long sec[4], snc[4];
    const int wid = tid >> 6, lane = tid & 63;
    if (lane == 0) { ses[wid] = es; sns[wid] = ns; sec[wid] = ec; snc[wid] = nc; }
    __syncthreads();
    if (tid == 0) {
        double tes = 0.0, tns = 0.0;
        long long tec = 0, tnc = 0;
#pragma unroll
        for (int w = 0; w < 4; ++w) { tes += ses[w]; tns += sns[w]; tec += sec[w]; tnc += snc[w]; }
        double ecd = (double)tec; if (ecd < 1.0) ecd = 1.0;
        double ncd = (double)tnc; if (ncd < 1.0) ncd = 1.0;
        out[0] = (float)((tes / ecd) * 0.01 + (tns / ncd) * 0.01);
    }
}

extern "C" void kernel_launch(void* const* d_in, const int* in_sizes, int n_in,
                              void* d_out, int out_size, void* d_ws, size_t ws_size,
                              hipStream_t stream) {
    const float* preds      = (const float*)d_in[0];  // (2,19,64,64) fp32
    const int*   targets    = (const int*)d_in[1];    // (2,512,512) int32
    const float* w_edge     = (const float*)d_in[2];  // (1,1,1,19,1,3) fp32
    const float* w_not_edge = (const float*)d_in[3];

    Part* pb = (Part*)d_ws;   // 2048 * 16 B; every slot written by k_fused

    dim3 grid(WW / TS, HH / TS, NB);   // 32 x 32 x 2 = 2048 blocks
    k_fused<<<grid, 256, 0, stream>>>(preds, targets, w_edge, w_not_edge, pb);
    k_final<<<1, 256, 0, stream>>>(pb, (float*)d_out);
}

// Round 6
// 97.651 us; speedup vs baseline: 1.0077x; 1.0077x over previous
//
#include <hip/hip_runtime.h>
#include <stdint.h>

// AAF loss, round 18 (retry; previous submission died in container
// acquisition, not compile/validate): R17 re-pairing algorithm (validated
// correct) with the register-pressure spill fixed. R17 regressed 29->41 us
// from scratch spill (WRITE_SIZE 2->18 MB, VGPR 48 = demoted arrays): the
// 20-word aw_/lw_ staging + Lh[10] + late own-label recompute exceeded the
// 96-VGPR cap of __launch_bounds__(256,5).
// Fixes, algorithm unchanged:
//  (1) incremental ds_write_b64 stores per 2-pair step (no aw_/lw_ buffers)
//  (2) Lh[] dropped from regs; border-pad branch reads own l-row from LDS
//  (3) own-label scalars computed BEFORE the packing loop (bilinear temps
//      die early); 5 scalar out-params instead of struct pointer.
// Algorithm recap: stage-1 stores a-row (words 0..9), l-row (10..19), TL =
// lab<<16|f16(T), T = sum(a*d+l); regs keep d-pairs + SL,u,v,dlab,llab.
// Stage-2 deep: dot = T_N - fdot(a_N, d_own) - SL (10 fdot2); kl@labP for
// both ordered pairs from 2 LDS words at own-label offset + 1 log2; @labN
// terms arrive symmetrically from the neighbor (pre-weighted swe/swn[nlab]).
// Ring-1 blocks: per-neighbor E check with self-contained fallback; border
// blocks fully self-contained incl. pads + reverse-ignore gates.

#define NC 19
#define HH 512
#define WW 512
#define NB 2
#define TS 16
#define HS 18                          // TS + 2 halo
#define HP (HS * HS)                   // 324
#define ATRS 20                        // words: a-pairs 0..9, l-pairs 10..19
#define PS 25                          // 5x5 source patch per class
#define NBLK 2048
#define LOG2E 1.4426950408889634f
#define LN2 0.6931471805599453f
#define LOG2EPS -13.287712379549449f   // log2(1e-4)
#define K2F 4.3280851226668906f        // 3/ln2: KLD margin in log2 units
#define K2PAD 4.328125f                // (_Float16)K2F exactly (pad-slot value)

typedef _Float16 f16x2 __attribute__((ext_vector_type(2)));

#if __has_builtin(__builtin_amdgcn_exp2f)
#define EXP2F(x) __builtin_amdgcn_exp2f(x)
#else
#define EXP2F(x) __expf((x) * LN2)
#endif

#if __has_builtin(__builtin_amdgcn_fdot2)
#define FDOT2(a, b, c) __builtin_amdgcn_fdot2((a), (b), (c), false)
#else
#define FDOT2(a, b, c) fmaf((float)(a)[1], (float)(b)[1], fmaf((float)(a)[0], (float)(b)[0], (c)))
#endif

struct Part { float es, ns; unsigned int cnt, pad; };

union U32F2 { uint32_t u; f16x2 h; };
__device__ __forceinline__ uint32_t bc_u32(f16x2 v) { U32F2 x; x.h = v; return x.u; }
__device__ __forceinline__ f16x2 bc_h2(uint32_t v) { U32F2 x; x.u = v; return x.h; }
__device__ __forceinline__ float extf(f16x2 v, int h) { return h ? (float)v[1] : (float)v[0]; }

union U16H { uint16_t u; _Float16 h; };
__device__ __forceinline__ uint32_t pack_TL(int lab, float T) {
    U16H t; t.h = (_Float16)T;
    return ((uint32_t)lab << 16) | (uint32_t)t.u;
}
__device__ __forceinline__ float TL_T(uint32_t tl) {
    U16H t; t.u = (uint16_t)(tl & 0xFFFFu);
    return (float)t.h;
}

// One pixel's softmax -> a-row (words 0..9) + l-row (words 10..19) + TL.
// All log2 domain. KEEP: d-pairs kept in regs + 5 scalars.
// Returns label (255 = OOB pad).
template <bool KEEP>
__device__ __forceinline__ int pix_compute(const float* __restrict__ patch,
                                           const int* __restrict__ tg,
                                           int y, int x, int y0b, int x0b,
                                           uint32_t* __restrict__ ATrow,
                                           uint32_t* __restrict__ TLw,
                                           f16x2* __restrict__ Dh,
                                           float* __restrict__ SLp,
                                           float* __restrict__ up,
                                           float* __restrict__ vp,
                                           float* __restrict__ dlabp,
                                           float* __restrict__ llabp) {
    const bool oob = ((unsigned)y >= (unsigned)HH) | ((unsigned)x >= (unsigned)WW);
    if (oob) {
        const _Float16 aP = (_Float16)1e-4f;
        const uint32_t aPP = bc_u32((f16x2){aP, aP});
        const uint32_t aPL = bc_u32((f16x2){aP, (_Float16)0.0f});
        uint2 wv;
        wv.x = aPP; wv.y = aPP;
        *reinterpret_cast<uint2*>(ATrow + 0) = wv;
        *reinterpret_cast<uint2*>(ATrow + 2) = wv;
        *reinterpret_cast<uint2*>(ATrow + 4) = wv;
        *reinterpret_cast<uint2*>(ATrow + 6) = wv;
        wv.y = aPL;
        *reinterpret_cast<uint2*>(ATrow + 8) = wv;
        uint2 zv; zv.x = 0u; zv.y = 0u;
        *reinterpret_cast<uint2*>(ATrow + 10) = zv;
        *reinterpret_cast<uint2*>(ATrow + 12) = zv;
        *reinterpret_cast<uint2*>(ATrow + 14) = zv;
        *reinterpret_cast<uint2*>(ATrow + 16) = zv;
        *reinterpret_cast<uint2*>(ATrow + 18) = zv;
        *TLw = pack_TL(255, 0.0f);
        if (KEEP) {
            const _Float16 dP = (_Float16)LOG2EPS;
#pragma unroll
            for (int j = 0; j < 10; ++j)
                Dh[j] = (j < 9) ? (f16x2){dP, dP} : (f16x2){dP, (_Float16)0.0f};
            *SLp = 0.0f; *up = 0.0f; *vp = 0.0f; *dlabp = 0.0f; *llabp = 0.0f;
        }
        return 255;
    }

    const int lab = tg[(y << 9) + x];
    const float fy = (float)(y * 63) / 511.0f;
    const float fx = (float)(x * 63) / 511.0f;
    const int y0 = (int)fy, x0 = (int)fx;
    const float wy = fy - (float)y0, wx = fx - (float)x0;
    const int y1 = min(y0 + 1, 63), x1 = min(x0 + 1, 63);
    const float omwy = 1.0f - wy, omwx = 1.0f - wx;
    const float bw00 = omwy * omwx, bw01 = omwy * wx;
    const float bw10 = wy * omwx,   bw11 = wy * wx;
    const int o00 = (y0 - y0b) * 5 + (x0 - x0b);
    const int o01 = o00 + (x1 - x0);
    const int o10 = o00 + (y1 - y0) * 5;
    const int o11 = o10 + (x1 - x0);

    float v2[NC], w[NC];
    float s = 0.0f;
#pragma unroll
    for (int c = 0; c < NC; ++c) {
        const float* pc_ = &patch[c * PS];
        const float vv = fmaf(pc_[o00], bw00, fmaf(pc_[o01], bw01,
                          fmaf(pc_[o10], bw10, pc_[o11] * bw11)));
        v2[c] = vv;
        const float e = EXP2F(vv);
        w[c] = e;
        s += e;
    }
    const float inv = 1.0f / s;
    const float lns2 = __log2f(s);            // log2 p = v2 - lns2

    if (KEEP) {
        // own-label scalars now, while bilinear temps are still live
        const float* pl = &patch[lab * PS];
        const float vlab = fmaf(pl[o00], bw00, fmaf(pl[o01], bw01,
                            fmaf(pl[o10], bw10, pl[o11] * bw11)));
        const float p = EXP2F(vlab) * inv;
        const float la = fmaxf(vlab - lns2, LOG2EPS);
        const float aa = fmaxf(p, 1e-4f);
        const float lb = __log2f(fmaxf(1.0f - p, 1e-4f));
        const float dd = la - lb;
        *dlabp = dd; *llabp = lb;
        *up = fmaf(aa, dd, lb); *vp = aa;
    }

    float Tdd = 0.0f, SL = 0.0f;
#pragma unroll
    for (int jp = 0; jp < 10; jp += 2) {
        uint32_t aw0 = 0u, aw1 = 0u, lw0 = 0u, lw1 = 0u;
#pragma unroll
        for (int q = 0; q < 2; ++q) {
            const int j = jp + q;
            _Float16 a0h = (_Float16)0.0f, l0h = (_Float16)0.0f, d0h = (_Float16)0.0f;
            _Float16 a1h = (_Float16)0.0f, l1h = (_Float16)0.0f, d1h = (_Float16)0.0f;
            {
                const int c = 2 * j;
                const float p = w[c] * inv;
                const float la = fmaxf(v2[c] - lns2, LOG2EPS);
                const float aa = fmaxf(p, 1e-4f);
                const float lb = __log2f(fmaxf(1.0f - p, 1e-4f));
                const float dd = la - lb;
                Tdd = fmaf(aa, dd, Tdd); SL += lb;
                a0h = (_Float16)aa; l0h = (_Float16)lb; d0h = (_Float16)dd;
            }
            if (2 * j + 1 < NC) {
                const int c = 2 * j + 1;
                const float p = w[c] * inv;
                const float la = fmaxf(v2[c] - lns2, LOG2EPS);
                const float aa = fmaxf(p, 1e-4f);
                const float lb = __log2f(fmaxf(1.0f - p, 1e-4f));
                const float dd = la - lb;
                Tdd = fmaf(aa, dd, Tdd); SL += lb;
                a1h = (_Float16)aa; l1h = (_Float16)lb; d1h = (_Float16)dd;
            }
            if (q == 0) { aw0 = bc_u32((f16x2){a0h, a1h}); lw0 = bc_u32((f16x2){l0h, l1h}); }
            else        { aw1 = bc_u32((f16x2){a0h, a1h}); lw1 = bc_u32((f16x2){l0h, l1h}); }
            if (KEEP) Dh[j] = (f16x2){d0h, d1h};
        }
        uint2 av; av.x = aw0; av.y = aw1;
        uint2 lv; lv.x = lw0; lv.y = lw1;
        *reinterpret_cast<uint2*>(ATrow + jp) = av;        // ds_write_b64
        *reinterpret_cast<uint2*>(ATrow + 10 + jp) = lv;   // ds_write_b64
    }
    *TLw = pack_TL(lab, Tdd + SL);
    if (KEEP) *SLp = SL;
    return lab;
}

__global__ __launch_bounds__(256, 5) void k_fused(const float* __restrict__ preds,
                                                  const int* __restrict__ targets,
                                                  const float* __restrict__ w_edge,
                                                  const float* __restrict__ w_not_edge,
                                                  Part* __restrict__ pb) {
    __shared__ __align__(16) uint32_t AT[HP * ATRS];  // 25,920 B
    __shared__ uint32_t TL[HP];                       // 1,296 B (lab<<16 | f16 T)
    __shared__ float2 swen[NC];                       // (swe, swn), ln2-folded
    __shared__ float patch[NC * PS];
    __shared__ float r_es[4], r_ns[4];
    __shared__ unsigned int r_cnt[4];

    const int tid = threadIdx.x;
    const int bx = blockIdx.x, by = blockIdx.y, n = blockIdx.z;

    if (tid < NC) {
        float sw_e, sw_n;
        {
            float a = w_edge[tid * 3 + 0], b = w_edge[tid * 3 + 1], c = w_edge[tid * 3 + 2];
            float m = fmaxf(a, fmaxf(b, c));
            float ea = __expf(a - m), eb = __expf(b - m), ec = __expf(c - m);
            sw_e = (ea / (ea + eb + ec)) * LN2;
        }
        {
            float a = w_not_edge[tid * 3 + 0], b = w_not_edge[tid * 3 + 1], c = w_not_edge[tid * 3 + 2];
            float m = fmaxf(a, fmaxf(b, c));
            float ea = __expf(a - m), eb = __expf(b - m), ec = __expf(c - m);
            sw_n = (ea / (ea + eb + ec)) * LN2;
        }
        swen[tid] = make_float2(sw_e, sw_n);
    }

    const int* tg = targets + (n << 18);
    const float* pbase = preds + (size_t)n * NC * 4096;

    const int ty = tid >> 4, tx = tid & 15;
    const int hi = (ty + 1) * HS + (tx + 1);
    const int DOFF[8] = {-HS - 1, -HS, -HS + 1, -1, 1, HS - 1, HS, HS + 1};
    const int DY[8] = {-1, -1, -1, 0, 0, 1, 1, 1};
    const int DX[8] = {-1, 0, 1, -1, 1, -1, 0, 1};
    const f16x2 one2 = {(_Float16)1.0f, (_Float16)1.0f};
    const f16x2 k32 = {(_Float16)K2F, (_Float16)K2F};

    float e_s = 0.0f, ne_s = 0.0f;
    unsigned int cnt = 0;               // e_c << 16 | ne_c

    // ---- stage 0: stage 5x5x19 source patch, pre-scaled by log2e ----
    const int yT = max(by * TS - 1, 0), xL = max(bx * TS - 1, 0);
    const int y0b = (yT * 63) / 511, x0b = (xL * 63) / 511;
    for (int t = tid; t < NC * PS; t += 256) {
        const int c = t / PS, r = t - c * PS;
        const int ry = r / 5, rx = r - ry * 5;
        const int sy = min(y0b + ry, 63), sx = min(x0b + rx, 63);
        patch[t] = pbase[c * 4096 + (sy << 6) + sx] * LOG2E;
    }
    __syncthreads();

    // ---- stage 1: halo ring first (temps die), then own pixel ----
    if (tid < 68) {
        int i;
        if (tid < 18)      i = tid;                       // top row
        else if (tid < 36) i = 306 + (tid - 18);          // bottom row
        else if (tid < 52) i = (tid - 35) * HS;           // left col (rows 1..16)
        else               i = (tid - 51) * HS + 17;      // right col (rows 1..16)
        const int hy = i / HS, hx = i - hy * HS;
        pix_compute<false>(patch, tg, by * TS + hy - 1, bx * TS + hx - 1,
                           y0b, x0b, &AT[i * ATRS], &TL[i],
                           nullptr, nullptr, nullptr, nullptr, nullptr, nullptr);
    }

    f16x2 Dh[10];
    float SL, u, v, dlab, llab;
    const int lab = pix_compute<true>(patch, tg, by * TS + ty, bx * TS + tx,
                                      y0b, x0b, &AT[hi * ATRS], &TL[hi],
                                      Dh, &SL, &u, &v, &dlab, &llab);
    __syncthreads();

    // ---- stage 2 ----
    const bool interior_blk = (bx > 0) & (bx < 31) & (by > 0) & (by < 31);
    const bool deep_blk = (bx > 1) & (bx < 30) & (by > 1) & (by < 30);
    const int plab = lab >> 1, hlab = lab & 1;
    const uint32_t* myrow = &AT[hi * ATRS];
    float es_o = 0.0f, ns_o = 0.0f;     // owner-weighted (x swen[lab] at end)
    float es_w = 0.0f, ns_w = 0.0f;     // pre-weighted reverse contributions

    if (deep_blk) {
#pragma unroll
        for (int k = 0; k < 8; ++k) {
            const int np = hi + DOFF[k];
            const uint32_t tl = TL[np];
            const int nlab = (int)(tl >> 16);
            const float T_N = TL_T(tl);
            const uint32_t* rb = &AT[np * ATRS];
            const uint4 A0 = *reinterpret_cast<const uint4*>(rb);
            const uint4 A1 = *reinterpret_cast<const uint4*>(rb + 4);
            const uint2 A2 = *reinterpret_cast<const uint2*>(rb + 8);
            float acc = 0.0f;
            acc = FDOT2(bc_h2(A0.x), Dh[0], acc);
            acc = FDOT2(bc_h2(A0.y), Dh[1], acc);
            acc = FDOT2(bc_h2(A0.z), Dh[2], acc);
            acc = FDOT2(bc_h2(A0.w), Dh[3], acc);
            acc = FDOT2(bc_h2(A1.x), Dh[4], acc);
            acc = FDOT2(bc_h2(A1.y), Dh[5], acc);
            acc = FDOT2(bc_h2(A1.z), Dh[6], acc);
            acc = FDOT2(bc_h2(A1.w), Dh[7], acc);
            acc = FDOT2(bc_h2(A2.x), Dh[8], acc);
            acc = FDOT2(bc_h2(A2.y), Dh[9], acc);
            const float dot = T_N - acc - SL;
            const float aN = extf(bc_h2(rb[plab]), hlab);      // a_N[lab]
            const float lN = extf(bc_h2(rb[10 + plab]), hlab); // l_N[lab]
            const float dN = __log2f(aN) - lN;
            const float klL = fmaf(aN, dN, lN) - fmaf(aN, dlab, llab); // kl(P,N)@labP
            const float klR = u - fmaf(v, dN, lN);                      // kl(N,P)@labP
            const bool df = (lab != nlab);
            const float wg = df ? 1.0f : 0.0f;
            const float2 sw = swen[nlab];
            es_o = fmaf(wg, fmaxf(K2F - klL, 0.0f), es_o);
            ns_o += dot - wg * klL;
            es_w = fmaf(wg * sw.x, fmaxf(K2F - klR, 0.0f), es_w);
            ns_w = fmaf(-wg * sw.y, klR, ns_w);
            cnt += df ? ((2u << 16) | (NC - 2)) : NC;
        }
    } else if (interior_blk) {
        const int gy = by * TS + ty, gx = bx * TS + tx;
#pragma unroll
        for (int k = 0; k < 8; ++k) {
            const int np = hi + DOFF[k];
            const uint32_t tl = TL[np];
            const int nlab = (int)(tl >> 16);
            const float T_N = TL_T(tl);
            const uint32_t* rb = &AT[np * ATRS];
            const uint4 A0 = *reinterpret_cast<const uint4*>(rb);
            const uint4 A1 = *reinterpret_cast<const uint4*>(rb + 4);
            const uint2 A2 = *reinterpret_cast<const uint2*>(rb + 8);
            float acc = 0.0f;
            acc = FDOT2(bc_h2(A0.x), Dh[0], acc);
            acc = FDOT2(bc_h2(A0.y), Dh[1], acc);
            acc = FDOT2(bc_h2(A0.z), Dh[2], acc);
            acc = FDOT2(bc_h2(A0.w), Dh[3], acc);
            acc = FDOT2(bc_h2(A1.x), Dh[4], acc);
            acc = FDOT2(bc_h2(A1.y), Dh[5], acc);
            acc = FDOT2(bc_h2(A1.z), Dh[6], acc);
            acc = FDOT2(bc_h2(A1.w), Dh[7], acc);
            acc = FDOT2(bc_h2(A2.x), Dh[8], acc);
            acc = FDOT2(bc_h2(A2.y), Dh[9], acc);
            const float dot = T_N - acc - SL;
            const float aN = extf(bc_h2(rb[plab]), hlab);
            const float lN = extf(bc_h2(rb[10 + plab]), hlab);
            const float dN = __log2f(aN) - lN;
            const float klL = fmaf(aN, dN, lN) - fmaf(aN, dlab, llab);
            const bool df = (lab != nlab);
            const float wg = df ? 1.0f : 0.0f;
            const int gyN = gy + DY[k], gxN = gx + DX[k];
            const bool E = ((unsigned)(gyN - 16) < 480u) & ((unsigned)(gxN - 16) < 480u);
            if (E) {
                const float klR = u - fmaf(v, dN, lN);
                const float2 sw = swen[nlab];
                es_o = fmaf(wg, fmaxf(K2F - klL, 0.0f), es_o);
                ns_o += dot - wg * klL;
                es_w = fmaf(wg * sw.x, fmaxf(K2F - klR, 0.0f), es_w);
                ns_w = fmaf(-wg * sw.y, klR, ns_w);
            } else {
                // self-contained: neighbor in border block (in-image, no pad)
                const int pn = nlab >> 1, hn = nlab & 1;
                const float aN2 = extf(bc_h2(rb[pn]), hn);        // a_N[nlab]
                const float lN2 = extf(bc_h2(rb[10 + pn]), hn);   // l_N[nlab]
                const float dN2 = __log2f(aN2) - lN2;
                const float ao = extf(bc_h2(myrow[pn]), hn);      // a_own[nlab]
                const float lo = extf(bc_h2(myrow[10 + pn]), hn); // l_own[nlab]
                const float doo = __log2f(ao) - lo;
                const float klN = fmaf(aN2, dN2, lN2) - fmaf(aN2, doo, lo);
                es_o = fmaf(wg, fmaxf(K2F - klL, 0.0f) + fmaxf(K2F - klN, 0.0f), es_o);
                ns_o += dot - wg * (klL + klN);
            }
            cnt += df ? ((2u << 16) | (NC - 2)) : NC;
        }
    } else if (lab <= NC - 1) {
        // ---- border path: self-contained, pads + reverse-ignore gates ----
        const _Float16 aP = (_Float16)1e-4f, dP = (_Float16)LOG2EPS;
        const _Float16 tP = (_Float16)((float)aP * (float)dP);
#pragma unroll
        for (int k = 0; k < 8; ++k) {
            const int off = DOFF[k];
            const int rlab = (int)(TL[hi - off] >> 16);
            const bool rvalid = (rlab <= NC - 1);
            const int np = hi + off;
            const uint32_t tl = TL[np];
            const int nlab = (int)(tl >> 16);
            const bool isPad = (nlab == 255);
            float ek_k, nk_k;
            unsigned int pc;
            if (isPad) {
                // pad neighbor: a=1e-4, t=a*LOG2EPS in all real slots; own l
                // read back from LDS (Lh no longer in regs)
                float ekall = 0.0f;
#pragma unroll
                for (int j = 0; j < 10; j += 2) {
                    const uint2 lr = *reinterpret_cast<const uint2*>(myrow + 10 + j);
                    const f16x2 l20 = bc_h2(lr.x);
                    const f16x2 l21 = bc_h2(lr.y);
                    const f16x2 a20 = {aP, aP};
                    const f16x2 t20 = {tP, tP};
                    const f16x2 a21 = (j + 1 < 9) ? (f16x2){aP, aP} : (f16x2){aP, (_Float16)0.0f};
                    const f16x2 t21 = (j + 1 < 9) ? (f16x2){tP, tP} : (f16x2){tP, (_Float16)0.0f};
                    f16x2 kl0 = t20 - (a20 * Dh[j] + l20);
                    f16x2 kl1 = t21 - (a21 * Dh[j + 1] + l21);
                    f16x2 m0 = k32 - kl0, m1 = k32 - kl1;
                    m0[0] = m0[0] > (_Float16)0.0f ? m0[0] : (_Float16)0.0f;
                    m0[1] = m0[1] > (_Float16)0.0f ? m0[1] : (_Float16)0.0f;
                    m1[0] = m1[0] > (_Float16)0.0f ? m1[0] : (_Float16)0.0f;
                    m1[1] = m1[1] > (_Float16)0.0f ? m1[1] : (_Float16)0.0f;
                    ekall = FDOT2(m0, one2, ekall);
                    ekall = FDOT2(m1, one2, ekall);
                }
                ek_k = ekall - K2PAD;   // drop zero-pad slot (kl=0 -> K2)
                nk_k = 0.0f;
                pc = NC;
            } else {
                const float T_N = TL_T(tl);
                const uint32_t* rb = &AT[np * ATRS];
                const uint4 A0 = *reinterpret_cast<const uint4*>(rb);
                const uint4 A1 = *reinterpret_cast<const uint4*>(rb + 4);
                const uint2 A2 = *reinterpret_cast<const uint2*>(rb + 8);
                float acc = 0.0f;
                acc = FDOT2(bc_h2(A0.x), Dh[0], acc);
                acc = FDOT2(bc_h2(A0.y), Dh[1], acc);
                acc = FDOT2(bc_h2(A0.z), Dh[2], acc);
                acc = FDOT2(bc_h2(A0.w), Dh[3], acc);
                acc = FDOT2(bc_h2(A1.x), Dh[4], acc);
                acc = FDOT2(bc_h2(A1.y), Dh[5], acc);
                acc = FDOT2(bc_h2(A1.z), Dh[6], acc);
                acc = FDOT2(bc_h2(A1.w), Dh[7], acc);
                acc = FDOT2(bc_h2(A2.x), Dh[8], acc);
                acc = FDOT2(bc_h2(A2.y), Dh[9], acc);
                const float dot = T_N - acc - SL;
                const float aN = extf(bc_h2(rb[plab]), hlab);
                const float lN = extf(bc_h2(rb[10 + plab]), hlab);
                const float dN = __log2f(aN) - lN;
                const float klL = fmaf(aN, dN, lN) - fmaf(aN, dlab, llab);
                const int pn = nlab >> 1, hn = nlab & 1;
                const float aN2 = extf(bc_h2(rb[pn]), hn);
                const float lN2 = extf(bc_h2(rb[10 + pn]), hn);
                const float dN2 = __log2f(aN2) - lN2;
                const float ao = extf(bc_h2(myrow[pn]), hn);
                const float lo = extf(bc_h2(myrow[10 + pn]), hn);
                const float doo = __log2f(ao) - lo;
                const float klN = fmaf(aN2, dN2, lN2) - fmaf(aN2, doo, lo);
                const bool df = (lab != nlab);
                const float wg = df ? 1.0f : 0.0f;
                ek_k = wg * (fmaxf(K2F - klL, 0.0f) + fmaxf(K2F - klN, 0.0f));
                nk_k = dot - wg * (klL + klN);
                pc = df ? 2u : 0u;
            }
            const float vf = rvalid ? 1.0f : 0.0f;
            es_o = fmaf(vf, ek_k, es_o);
            ns_o = fmaf(vf, nk_k, ns_o);
            cnt += rvalid ? ((pc << 16) | (NC - pc)) : 0u;
        }
    }

    {
        const float2 swl = swen[lab <= NC - 1 ? lab : 0];
        e_s  = fmaf(es_o, swl.x, es_w);
        ne_s = fmaf(ns_o, swl.y, ns_w);
    }

    // ---- block reduction ----
#pragma unroll
    for (int off = 32; off > 0; off >>= 1) {
        e_s  += __shfl_down(e_s, off, 64);
        ne_s += __shfl_down(ne_s, off, 64);
        cnt  += __shfl_down(cnt, off, 64);
    }
    const int wid = tid >> 6, lane = tid & 63;
    if (lane == 0) { r_es[wid] = e_s; r_ns[wid] = ne_s; r_cnt[wid] = cnt; }
    __syncthreads();
    if (tid == 0) {
        float tes = 0.0f, tns = 0.0f;
        unsigned int tc = 0;
#pragma unroll
        for (int w = 0; w < 4; ++w) { tes += r_es[w]; tns += r_ns[w]; tc += r_cnt[w]; }
        const int bid = (blockIdx.z * gridDim.y + blockIdx.y) * gridDim.x + blockIdx.x;
        pb[bid].es = tes; pb[bid].ns = tns; pb[bid].cnt = tc; pb[bid].pad = 0;
    }
}

// ---------------- final reduce (1 block) ----------------
__global__ __launch_bounds__(256) void k_final(const Part* __restrict__ pb,
                                               float* __restrict__ out) {
    const int tid = threadIdx.x;
    double es = 0.0, ns = 0.0;
    long long ec = 0, nc = 0;
    for (int i = tid; i < NBLK; i += 256) {
        es += (double)pb[i].es; ns += (double)pb[i].ns;
        const unsigned int c = pb[i].cnt;
        ec += (long long)(c >> 16); nc += (long long)(c & 0xFFFFu);
    }
#pragma unroll
    for (int off = 32; off > 0; off >>= 1) {
        es += __shfl_down(es, off, 64);
        ns += __shfl_down(ns, off, 64);
        ec += __shfl_down(ec, off, 64);
        nc += __shfl_down(nc, off, 64);
    }
    __shared__ double ses[4], sns[4];
    __shared__ long long sec[4], snc[4];
    const int wid = tid >> 6, lane = tid & 63;
    if (lane == 0) { ses[wid] = es; sns[wid] = ns; sec[wid] = ec; snc[wid] = nc; }
    __syncthreads();
    if (tid == 0) {
        double tes = 0.0, tns = 0.0;
        long long tec = 0, tnc = 0;
#pragma unroll
        for (int w = 0; w < 4; ++w) { tes += ses[w]; tns += sns[w]; tec += sec[w]; tnc += snc[w]; }
        double ecd = (double)tec; if (ecd < 1.0) ecd = 1.0;
        double ncd = (double)tnc; if (ncd < 1.0) ncd = 1.0;
        out[0] = (float)((tes / ecd) * 0.01 + (tns / ncd) * 0.01);
    }
}

extern "C" void kernel_launch(void* const* d_in, const int* in_sizes, int n_in,
                              void* d_out, int out_size, void* d_ws, size_t ws_size,
                              hipStream_t stream) {
    const float* preds      = (const float*)d_in[0];  // (2,19,64,64) fp32
    const int*   targets    = (const int*)d_in[1];    // (2,512,512) int32
    const float* w_edge     = (const float*)d_in[2];  // (1,1,1,19,1,3) fp32
    const float* w_not_edge = (const float*)d_in[3];

    Part* pb = (Part*)d_ws;   // 2048 * 16 B; every slot written by k_fused

    dim3 grid(WW / TS, HH / TS, NB);   // 32 x 32 x 2 = 2048 blocks
    k_fused<<<grid, 256, 0, stream>>>(preds, targets, w_edge, w_not_edge, pb);
    k_final<<<1, 256, 0, stream>>>(pb, (float*)d_out);
}

// Round 7
// 97.204 us; speedup vs baseline: 1.0124x; 1.0046x over previous
//
#include <hip/hip_runtime.h>
#include <stdint.h>

// AAF loss, round 19: fit the re-pairing kernel under the 64-VGPR occupancy
// step. R18 still spilled (WRITE_SIZE 9 MB, VGPR 48): launch_bounds(256,5)
// effectively caps at 64 VGPRs (HW occupancy steps at 64/128/256), and
// v2[19]+w[19] alive through the packing loop + own-label recompute peaked
// ~75-80 live.
// Fixes (algorithm identical to validated R17/R18, absmax 0.0):
//  (1) w[] array deleted: packing loop recomputes p = exp2(v2[c]-lns2)
//      (one quarter-rate exp2 replaces a mul; inv reciprocal gone).
//  (2) own-label bilinear recompute deleted: after the own LDS row is
//      written, read a[lab],l[lab] back (2 words, same-thread RAW) and
//      derive dlab = log2(a)-l, u = fma(a,dlab,l). Also self-consistent
//      with what neighbors compute for the reverse-paired term.
// Stage-1 peak live ~50 < 64. Stage-2 unchanged.
// Algorithm recap: stage-1 stores a-row (words 0..9), l-row (10..19), TL =
// lab<<16|f16(T), T = sum(a*d+l); regs keep d-pairs + SL + own-label
// scalars. Stage-2 deep: dot = T_N - fdot(a_N, d_own) - SL (10 fdot2);
// kl@labP for both ordered pairs from 2 LDS words at own-label offset + 1
// log2; @labN terms arrive symmetrically from the neighbor (pre-weighted
// swe/swn[nlab]). Ring-1: per-neighbor E check with self-contained
// fallback; border blocks fully self-contained incl. pads + reverse gates.

#define NC 19
#define HH 512
#define WW 512
#define NB 2
#define TS 16
#define HS 18                          // TS + 2 halo
#define HP (HS * HS)                   // 324
#define ATRS 20                        // words: a-pairs 0..9, l-pairs 10..19
#define PS 25                          // 5x5 source patch per class
#define NBLK 2048
#define LOG2E 1.4426950408889634f
#define LN2 0.6931471805599453f
#define LOG2EPS -13.287712379549449f   // log2(1e-4)
#define K2F 4.3280851226668906f        // 3/ln2: KLD margin in log2 units
#define K2PAD 4.328125f                // (_Float16)K2F exactly (pad-slot value)

typedef _Float16 f16x2 __attribute__((ext_vector_type(2)));

#if __has_builtin(__builtin_amdgcn_exp2f)
#define EXP2F(x) __builtin_amdgcn_exp2f(x)
#else
#define EXP2F(x) __expf((x) * LN2)
#endif

#if __has_builtin(__builtin_amdgcn_fdot2)
#define FDOT2(a, b, c) __builtin_amdgcn_fdot2((a), (b), (c), false)
#else
#define FDOT2(a, b, c) fmaf((float)(a)[1], (float)(b)[1], fmaf((float)(a)[0], (float)(b)[0], (c)))
#endif

struct Part { float es, ns; unsigned int cnt, pad; };

union U32F2 { uint32_t u; f16x2 h; };
__device__ __forceinline__ uint32_t bc_u32(f16x2 v) { U32F2 x; x.h = v; return x.u; }
__device__ __forceinline__ f16x2 bc_h2(uint32_t v) { U32F2 x; x.u = v; return x.h; }
__device__ __forceinline__ float extf(f16x2 v, int h) { return h ? (float)v[1] : (float)v[0]; }

union U16H { uint16_t u; _Float16 h; };
__device__ __forceinline__ uint32_t pack_TL(int lab, float T) {
    U16H t; t.h = (_Float16)T;
    return ((uint32_t)lab << 16) | (uint32_t)t.u;
}
__device__ __forceinline__ float TL_T(uint32_t tl) {
    U16H t; t.u = (uint16_t)(tl & 0xFFFFu);
    return (float)t.h;
}

// One pixel's softmax -> a-row (words 0..9) + l-row (words 10..19) + TL.
// All log2 domain. KEEP: d-pairs kept in regs + SL.
// Returns label (255 = OOB pad).
template <bool KEEP>
__device__ __forceinline__ int pix_compute(const float* __restrict__ patch,
                                           const int* __restrict__ tg,
                                           int y, int x, int y0b, int x0b,
                                           uint32_t* __restrict__ ATrow,
                                           uint32_t* __restrict__ TLw,
                                           f16x2* __restrict__ Dh,
                                           float* __restrict__ SLp) {
    const bool oob = ((unsigned)y >= (unsigned)HH) | ((unsigned)x >= (unsigned)WW);
    if (oob) {
        const _Float16 aP = (_Float16)1e-4f;
        const uint32_t aPP = bc_u32((f16x2){aP, aP});
        const uint32_t aPL = bc_u32((f16x2){aP, (_Float16)0.0f});
        uint2 wv;
        wv.x = aPP; wv.y = aPP;
        *reinterpret_cast<uint2*>(ATrow + 0) = wv;
        *reinterpret_cast<uint2*>(ATrow + 2) = wv;
        *reinterpret_cast<uint2*>(ATrow + 4) = wv;
        *reinterpret_cast<uint2*>(ATrow + 6) = wv;
        wv.y = aPL;
        *reinterpret_cast<uint2*>(ATrow + 8) = wv;
        uint2 zv; zv.x = 0u; zv.y = 0u;
        *reinterpret_cast<uint2*>(ATrow + 10) = zv;
        *reinterpret_cast<uint2*>(ATrow + 12) = zv;
        *reinterpret_cast<uint2*>(ATrow + 14) = zv;
        *reinterpret_cast<uint2*>(ATrow + 16) = zv;
        *reinterpret_cast<uint2*>(ATrow + 18) = zv;
        *TLw = pack_TL(255, 0.0f);
        if (KEEP) {
            const _Float16 dP = (_Float16)LOG2EPS;
#pragma unroll
            for (int j = 0; j < 10; ++j)
                Dh[j] = (j < 9) ? (f16x2){dP, dP} : (f16x2){dP, (_Float16)0.0f};
            *SLp = 0.0f;
        }
        return 255;
    }

    const int lab = tg[(y << 9) + x];
    const float fy = (float)(y * 63) / 511.0f;
    const float fx = (float)(x * 63) / 511.0f;
    const int y0 = (int)fy, x0 = (int)fx;
    const float wy = fy - (float)y0, wx = fx - (float)x0;
    const int y1 = min(y0 + 1, 63), x1 = min(x0 + 1, 63);
    const float omwy = 1.0f - wy, omwx = 1.0f - wx;
    const float bw00 = omwy * omwx, bw01 = omwy * wx;
    const float bw10 = wy * omwx,   bw11 = wy * wx;
    const int o00 = (y0 - y0b) * 5 + (x0 - x0b);
    const int o01 = o00 + (x1 - x0);
    const int o10 = o00 + (y1 - y0) * 5;
    const int o11 = o10 + (x1 - x0);

    // v2 = logits*log2e (patch pre-scaled). Only v2[] is kept; exp results
    // are consumed into the sum immediately (w[] array deleted -> -19 VGPR).
    float v2[NC];
    float s = 0.0f;
#pragma unroll
    for (int c = 0; c < NC; ++c) {
        const float* pc_ = &patch[c * PS];
        const float vv = fmaf(pc_[o00], bw00, fmaf(pc_[o01], bw01,
                          fmaf(pc_[o10], bw10, pc_[o11] * bw11)));
        v2[c] = vv;
        s += EXP2F(vv);
    }
    const float lns2 = __log2f(s);            // log2 p = v2 - lns2

    float Tdd = 0.0f, SL = 0.0f;
#pragma unroll
    for (int jp = 0; jp < 10; jp += 2) {
        uint32_t aw0 = 0u, aw1 = 0u, lw0 = 0u, lw1 = 0u;
#pragma unroll
        for (int q = 0; q < 2; ++q) {
            const int j = jp + q;
            _Float16 a0h = (_Float16)0.0f, l0h = (_Float16)0.0f, d0h = (_Float16)0.0f;
            _Float16 a1h = (_Float16)0.0f, l1h = (_Float16)0.0f, d1h = (_Float16)0.0f;
            {
                const int c = 2 * j;
                const float lr = v2[c] - lns2;        // log2 p (unclipped)
                const float p = EXP2F(lr);
                const float la = fmaxf(lr, LOG2EPS);
                const float aa = fmaxf(p, 1e-4f);
                const float lb = __log2f(fmaxf(1.0f - p, 1e-4f));
                const float dd = la - lb;
                Tdd = fmaf(aa, dd, Tdd); SL += lb;
                a0h = (_Float16)aa; l0h = (_Float16)lb; d0h = (_Float16)dd;
            }
            if (2 * j + 1 < NC) {
                const int c = 2 * j + 1;
                const float lr = v2[c] - lns2;
                const float p = EXP2F(lr);
                const float la = fmaxf(lr, LOG2EPS);
                const float aa = fmaxf(p, 1e-4f);
                const float lb = __log2f(fmaxf(1.0f - p, 1e-4f));
                const float dd = la - lb;
                Tdd = fmaf(aa, dd, Tdd); SL += lb;
                a1h = (_Float16)aa; l1h = (_Float16)lb; d1h = (_Float16)dd;
            }
            if (q == 0) { aw0 = bc_u32((f16x2){a0h, a1h}); lw0 = bc_u32((f16x2){l0h, l1h}); }
            else        { aw1 = bc_u32((f16x2){a0h, a1h}); lw1 = bc_u32((f16x2){l0h, l1h}); }
            if (KEEP) Dh[j] = (f16x2){d0h, d1h};
        }
        uint2 av; av.x = aw0; av.y = aw1;
        uint2 lv; lv.x = lw0; lv.y = lw1;
        *reinterpret_cast<uint2*>(ATrow + jp) = av;        // ds_write_b64
        *reinterpret_cast<uint2*>(ATrow + 10 + jp) = lv;   // ds_write_b64
    }
    *TLw = pack_TL(lab, Tdd + SL);
    if (KEEP) *SLp = SL;
    return lab;
}

__global__ __launch_bounds__(256, 5) void k_fused(const float* __restrict__ preds,
                                                  const int* __restrict__ targets,
                                                  const float* __restrict__ w_edge,
                                                  const float* __restrict__ w_not_edge,
                                                  Part* __restrict__ pb) {
    __shared__ __align__(16) uint32_t AT[HP * ATRS];  // 25,920 B
    __shared__ uint32_t TL[HP];                       // 1,296 B (lab<<16 | f16 T)
    __shared__ float2 swen[NC];                       // (swe, swn), ln2-folded
    __shared__ float patch[NC * PS];
    __shared__ float r_es[4], r_ns[4];
    __shared__ unsigned int r_cnt[4];

    const int tid = threadIdx.x;
    const int bx = blockIdx.x, by = blockIdx.y, n = blockIdx.z;

    if (tid < NC) {
        float sw_e, sw_n;
        {
            float a = w_edge[tid * 3 + 0], b = w_edge[tid * 3 + 1], c = w_edge[tid * 3 + 2];
            float m = fmaxf(a, fmaxf(b, c));
            float ea = __expf(a - m), eb = __expf(b - m), ec = __expf(c - m);
            sw_e = (ea / (ea + eb + ec)) * LN2;
        }
        {
            float a = w_not_edge[tid * 3 + 0], b = w_not_edge[tid * 3 + 1], c = w_not_edge[tid * 3 + 2];
            float m = fmaxf(a, fmaxf(b, c));
            float ea = __expf(a - m), eb = __expf(b - m), ec = __expf(c - m);
            sw_n = (ea / (ea + eb + ec)) * LN2;
        }
        swen[tid] = make_float2(sw_e, sw_n);
    }

    const int* tg = targets + (n << 18);
    const float* pbase = preds + (size_t)n * NC * 4096;

    const int ty = tid >> 4, tx = tid & 15;
    const int hi = (ty + 1) * HS + (tx + 1);
    const int DOFF[8] = {-HS - 1, -HS, -HS + 1, -1, 1, HS - 1, HS, HS + 1};
    const int DY[8] = {-1, -1, -1, 0, 0, 1, 1, 1};
    const int DX[8] = {-1, 0, 1, -1, 1, -1, 0, 1};
    const f16x2 one2 = {(_Float16)1.0f, (_Float16)1.0f};
    const f16x2 k32 = {(_Float16)K2F, (_Float16)K2F};

    float e_s = 0.0f, ne_s = 0.0f;
    unsigned int cnt = 0;               // e_c << 16 | ne_c

    // ---- stage 0: stage 5x5x19 source patch, pre-scaled by log2e ----
    const int yT = max(by * TS - 1, 0), xL = max(bx * TS - 1, 0);
    const int y0b = (yT * 63) / 511, x0b = (xL * 63) / 511;
    for (int t = tid; t < NC * PS; t += 256) {
        const int c = t / PS, r = t - c * PS;
        const int ry = r / 5, rx = r - ry * 5;
        const int sy = min(y0b + ry, 63), sx = min(x0b + rx, 63);
        patch[t] = pbase[c * 4096 + (sy << 6) + sx] * LOG2E;
    }
    __syncthreads();

    // ---- stage 1: halo ring first (temps die), then own pixel ----
    if (tid < 68) {
        int i;
        if (tid < 18)      i = tid;                       // top row
        else if (tid < 36) i = 306 + (tid - 18);          // bottom row
        else if (tid < 52) i = (tid - 35) * HS;           // left col (rows 1..16)
        else               i = (tid - 51) * HS + 17;      // right col (rows 1..16)
        const int hy = i / HS, hx = i - hy * HS;
        pix_compute<false>(patch, tg, by * TS + hy - 1, bx * TS + hx - 1,
                           y0b, x0b, &AT[i * ATRS], &TL[i], nullptr, nullptr);
    }

    const uint32_t* myrow = &AT[hi * ATRS];
    f16x2 Dh[10];
    float SL;
    const int lab = pix_compute<true>(patch, tg, by * TS + ty, bx * TS + tx,
                                      y0b, x0b, &AT[hi * ATRS], &TL[hi], Dh, &SL);
    // Own-label scalars from the just-written row (same-thread RAW; also the
    // exact f16 values neighbors use for the reverse-paired terms).
    const int plab = lab >> 1, hlab = lab & 1;
    const float aown = extf(bc_h2(myrow[plab]), hlab);
    const float llab = extf(bc_h2(myrow[10 + plab]), hlab);
    const float dlab = __log2f(aown) - llab;
    const float u = fmaf(aown, dlab, llab);
    __syncthreads();

    // ---- stage 2 ----
    const bool interior_blk = (bx > 0) & (bx < 31) & (by > 0) & (by < 31);
    const bool deep_blk = (bx > 1) & (bx < 30) & (by > 1) & (by < 30);
    float es_o = 0.0f, ns_o = 0.0f;     // owner-weighted (x swen[lab] at end)
    float es_w = 0.0f, ns_w = 0.0f;     // pre-weighted reverse contributions

    if (deep_blk) {
#pragma unroll
        for (int k = 0; k < 8; ++k) {
            const int np = hi + DOFF[k];
            const uint32_t tl = TL[np];
            const int nlab = (int)(tl >> 16);
            const float T_N = TL_T(tl);
            const uint32_t* rb = &AT[np * ATRS];
            const uint4 A0 = *reinterpret_cast<const uint4*>(rb);
            const uint4 A1 = *reinterpret_cast<const uint4*>(rb + 4);
            const uint2 A2 = *reinterpret_cast<const uint2*>(rb + 8);
            float acc = 0.0f;
            acc = FDOT2(bc_h2(A0.x), Dh[0], acc);
            acc = FDOT2(bc_h2(A0.y), Dh[1], acc);
            acc = FDOT2(bc_h2(A0.z), Dh[2], acc);
            acc = FDOT2(bc_h2(A0.w), Dh[3], acc);
            acc = FDOT2(bc_h2(A1.x), Dh[4], acc);
            acc = FDOT2(bc_h2(A1.y), Dh[5], acc);
            acc = FDOT2(bc_h2(A1.z), Dh[6], acc);
            acc = FDOT2(bc_h2(A1.w), Dh[7], acc);
            acc = FDOT2(bc_h2(A2.x), Dh[8], acc);
            acc = FDOT2(bc_h2(A2.y), Dh[9], acc);
            const float dot = T_N - acc - SL;
            const float aN = extf(bc_h2(rb[plab]), hlab);      // a_N[lab]
            const float lN = extf(bc_h2(rb[10 + plab]), hlab); // l_N[lab]
            const float dN = __log2f(aN) - lN;
            const float klL = fmaf(aN, dN, lN) - fmaf(aN, dlab, llab); // kl(P,N)@labP
            const float klR = u - fmaf(aown, dN, lN);                  // kl(N,P)@labP
            const bool df = (lab != nlab);
            const float wg = df ? 1.0f : 0.0f;
            const float2 sw = swen[nlab];
            es_o = fmaf(wg, fmaxf(K2F - klL, 0.0f), es_o);
            ns_o += dot - wg * klL;
            es_w = fmaf(wg * sw.x, fmaxf(K2F - klR, 0.0f), es_w);
            ns_w = fmaf(-wg * sw.y, klR, ns_w);
            cnt += df ? ((2u << 16) | (NC - 2)) : NC;
        }
    } else if (interior_blk) {
        const int gy = by * TS + ty, gx = bx * TS + tx;
#pragma unroll
        for (int k = 0; k < 8; ++k) {
            const int np = hi + DOFF[k];
            const uint32_t tl = TL[np];
            const int nlab = (int)(tl >> 16);
            const float T_N = TL_T(tl);
            const uint32_t* rb = &AT[np * ATRS];
            const uint4 A0 = *reinterpret_cast<const uint4*>(rb);
            const uint4 A1 = *reinterpret_cast<const uint4*>(rb + 4);
            const uint2 A2 = *reinterpret_cast<const uint2*>(rb + 8);
            float acc = 0.0f;
            acc = FDOT2(bc_h2(A0.x), Dh[0], acc);
            acc = FDOT2(bc_h2(A0.y), Dh[1], acc);
            acc = FDOT2(bc_h2(A0.z), Dh[2], acc);
            acc = FDOT2(bc_h2(A0.w), Dh[3], acc);
            acc = FDOT2(bc_h2(A1.x), Dh[4], acc);
            acc = FDOT2(bc_h2(A1.y), Dh[5], acc);
            acc = FDOT2(bc_h2(A1.z), Dh[6], acc);
            acc = FDOT2(bc_h2(A1.w), Dh[7], acc);
            acc = FDOT2(bc_h2(A2.x), Dh[8], acc);
            acc = FDOT2(bc_h2(A2.y), Dh[9], acc);
            const float dot = T_N - acc - SL;
            const float aN = extf(bc_h2(rb[plab]), hlab);
            const float lN = extf(bc_h2(rb[10 + plab]), hlab);
            const float dN = __log2f(aN) - lN;
            const float klL = fmaf(aN, dN, lN) - fmaf(aN, dlab, llab);
            const bool df = (lab != nlab);
            const float wg = df ? 1.0f : 0.0f;
            const int gyN = gy + DY[k], gxN = gx + DX[k];
            const bool E = ((unsigned)(gyN - 16) < 480u) & ((unsigned)(gxN - 16) < 480u);
            if (E) {
                const float klR = u - fmaf(aown, dN, lN);
                const float2 sw = swen[nlab];
                es_o = fmaf(wg, fmaxf(K2F - klL, 0.0f), es_o);
                ns_o += dot - wg * klL;
                es_w = fmaf(wg * sw.x, fmaxf(K2F - klR, 0.0f), es_w);
                ns_w = fmaf(-wg * sw.y, klR, ns_w);
            } else {
                // self-contained: neighbor in border block (in-image, no pad)
                const int pn = nlab >> 1, hn = nlab & 1;
                const float aN2 = extf(bc_h2(rb[pn]), hn);        // a_N[nlab]
                const float lN2 = extf(bc_h2(rb[10 + pn]), hn);   // l_N[nlab]
                const float dN2 = __log2f(aN2) - lN2;
                const float ao = extf(bc_h2(myrow[pn]), hn);      // a_own[nlab]
                const float lo = extf(bc_h2(myrow[10 + pn]), hn); // l_own[nlab]
                const float doo = __log2f(ao) - lo;
                const float klN = fmaf(aN2, dN2, lN2) - fmaf(aN2, doo, lo);
                es_o = fmaf(wg, fmaxf(K2F - klL, 0.0f) + fmaxf(K2F - klN, 0.0f), es_o);
                ns_o += dot - wg * (klL + klN);
            }
            cnt += df ? ((2u << 16) | (NC - 2)) : NC;
        }
    } else if (lab <= NC - 1) {
        // ---- border path: self-contained, pads + reverse-ignore gates ----
        const _Float16 aP = (_Float16)1e-4f, dP = (_Float16)LOG2EPS;
        const _Float16 tP = (_Float16)((float)aP * (float)dP);
#pragma unroll
        for (int k = 0; k < 8; ++k) {
            const int off = DOFF[k];
            const int rlab = (int)(TL[hi - off] >> 16);
            const bool rvalid = (rlab <= NC - 1);
            const int np = hi + off;
            const uint32_t tl = TL[np];
            const int nlab = (int)(tl >> 16);
            const bool isPad = (nlab == 255);
            float ek_k, nk_k;
            unsigned int pc;
            if (isPad) {
                // pad neighbor: a=1e-4, t=a*LOG2EPS in all real slots; own l
                // row read back from LDS
                float ekall = 0.0f;
#pragma unroll
                for (int j = 0; j < 10; j += 2) {
                    const uint2 lr = *reinterpret_cast<const uint2*>(myrow + 10 + j);
                    const f16x2 l20 = bc_h2(lr.x);
                    const f16x2 l21 = bc_h2(lr.y);
                    const f16x2 a20 = {aP, aP};
                    const f16x2 t20 = {tP, tP};
                    const f16x2 a21 = (j + 1 < 9) ? (f16x2){aP, aP} : (f16x2){aP, (_Float16)0.0f};
                    const f16x2 t21 = (j + 1 < 9) ? (f16x2){tP, tP} : (f16x2){tP, (_Float16)0.0f};
                    f16x2 kl0 = t20 - (a20 * Dh[j] + l20);
                    f16x2 kl1 = t21 - (a21 * Dh[j + 1] + l21);
                    f16x2 m0 = k32 - kl0, m1 = k32 - kl1;
                    m0[0] = m0[0] > (_Float16)0.0f ? m0[0] : (_Float16)0.0f;
                    m0[1] = m0[1] > (_Float16)0.0f ? m0[1] : (_Float16)0.0f;
                    m1[0] = m1[0] > (_Float16)0.0f ? m1[0] : (_Float16)0.0f;
                    m1[1] = m1[1] > (_Float16)0.0f ? m1[1] : (_Float16)0.0f;
                    ekall = FDOT2(m0, one2, ekall);
                    ekall = FDOT2(m1, one2, ekall);
                }
                ek_k = ekall - K2PAD;   // drop zero-pad slot (kl=0 -> K2)
                nk_k = 0.0f;
                pc = NC;
            } else {
                const float T_N = TL_T(tl);
                const uint32_t* rb = &AT[np * ATRS];
                const uint4 A0 = *reinterpret_cast<const uint4*>(rb);
                const uint4 A1 = *reinterpret_cast<const uint4*>(rb + 4);
                const uint2 A2 = *reinterpret_cast<const uint2*>(rb + 8);
                float acc = 0.0f;
                acc = FDOT2(bc_h2(A0.x), Dh[0], acc);
                acc = FDOT2(bc_h2(A0.y), Dh[1], acc);
                acc = FDOT2(bc_h2(A0.z), Dh[2], acc);
                acc = FDOT2(bc_h2(A0.w), Dh[3], acc);
                acc = FDOT2(bc_h2(A1.x), Dh[4], acc);
                acc = FDOT2(bc_h2(A1.y), Dh[5], acc);
                acc = FDOT2(bc_h2(A1.z), Dh[6], acc);
                acc = FDOT2(bc_h2(A1.w), Dh[7], acc);
                acc = FDOT2(bc_h2(A2.x), Dh[8], acc);
                acc = FDOT2(bc_h2(A2.y), Dh[9], acc);
                const float dot = T_N - acc - SL;
                const float aN = extf(bc_h2(rb[plab]), hlab);
                const float lN = extf(bc_h2(rb[10 + plab]), hlab);
                const float dN = __log2f(aN) - lN;
                const float klL = fmaf(aN, dN, lN) - fmaf(aN, dlab, llab);
                const int pn = nlab >> 1, hn = nlab & 1;
                const float aN2 = extf(bc_h2(rb[pn]), hn);
                const float lN2 = extf(bc_h2(rb[10 + pn]), hn);
                const float dN2 = __log2f(aN2) - lN2;
                const float ao = extf(bc_h2(myrow[pn]), hn);
                const float lo = extf(bc_h2(myrow[10 + pn]), hn);
                const float doo = __log2f(ao) - lo;
                const float klN = fmaf(aN2, dN2, lN2) - fmaf(aN2, doo, lo);
                const bool df = (lab != nlab);
                const float wg = df ? 1.0f : 0.0f;
                ek_k = wg * (fmaxf(K2F - klL, 0.0f) + fmaxf(K2F - klN, 0.0f));
                nk_k = dot - wg * (klL + klN);
                pc = df ? 2u : 0u;
            }
            const float vf = rvalid ? 1.0f : 0.0f;
            es_o = fmaf(vf, ek_k, es_o);
            ns_o = fmaf(vf, nk_k, ns_o);
            cnt += rvalid ? ((pc << 16) | (NC - pc)) : 0u;
        }
    }

    {
        const float2 swl = swen[lab <= NC - 1 ? lab : 0];
        e_s  = fmaf(es_o, swl.x, es_w);
        ne_s = fmaf(ns_o, swl.y, ns_w);
    }

    // ---- block reduction ----
#pragma unroll
    for (int off = 32; off > 0; off >>= 1) {
        e_s  += __shfl_down(e_s, off, 64);
        ne_s += __shfl_down(ne_s, off, 64);
        cnt  += __shfl_down(cnt, off, 64);
    }
    const int wid = tid >> 6, lane = tid & 63;
    if (lane == 0) { r_es[wid] = e_s; r_ns[wid] = ne_s; r_cnt[wid] = cnt; }
    __syncthreads();
    if (tid == 0) {
        float tes = 0.0f, tns = 0.0f;
        unsigned int tc = 0;
#pragma unroll
        for (int w = 0; w < 4; ++w) { tes += r_es[w]; tns += r_ns[w]; tc += r_cnt[w]; }
        const int bid = (blockIdx.z * gridDim.y + blockIdx.y) * gridDim.x + blockIdx.x;
        pb[bid].es = tes; pb[bid].ns = tns; pb[bid].cnt = tc; pb[bid].pad = 0;
    }
}

// ---------------- final reduce (1 block) ----------------
__global__ __launch_bounds__(256) void k_final(const Part* __restrict__ pb,
                                               float* __restrict__ out) {
    const int tid = threadIdx.x;
    double es = 0.0, ns = 0.0;
    long long ec = 0, nc = 0;
    for (int i = tid; i < NBLK; i += 256) {
        es += (double)pb[i].es; ns += (double)pb[i].ns;
        const unsigned int c = pb[i].cnt;
        ec += (long long)(c >> 16); nc += (long long)(c & 0xFFFFu);
    }
#pragma unroll
    for (int off = 32; off > 0; off >>= 1) {
        es += __shfl_down(es, off, 64);
        ns += __shfl_down(ns, off, 64);
        ec += __shfl_down(ec, off, 64);
        nc += __shfl_down(nc, off, 64);
    }
    __shared__ double ses[4], sns[4];
    __shared__ long long sec[4], snc[4];
    const int wid = tid >> 6, lane = tid & 63;
    if (lane == 0) { ses[wid] = es; sns[wid] = ns; sec[wid] = ec; snc[wid] = nc; }
    __syncthreads();
    if (tid == 0) {
        double tes = 0.0, tns = 0.0;
        long long tec = 0, tnc = 0;
#pragma unroll
        for (int w = 0; w < 4; ++w) { tes += ses[w]; tns += sns[w]; tec += sec[w]; tnc += snc[w]; }
        double ecd = (double)tec; if (ecd < 1.0) ecd = 1.0;
        double ncd = (double)tnc; if (ncd < 1.0) ncd = 1.0;
        out[0] = (float)((tes / ecd) * 0.01 + (tns / ncd) * 0.01);
    }
}

extern "C" void kernel_launch(void* const* d_in, const int* in_sizes, int n_in,
                              void* d_out, int out_size, void* d_ws, size_t ws_size,
                              hipStream_t stream) {
    const float* preds      = (const float*)d_in[0];  // (2,19,64,64) fp32
    const int*   targets    = (const int*)d_in[1];    // (2,512,512) int32
    const float* w_edge     = (const float*)d_in[2];  // (1,1,1,19,1,3) fp32
    const float* w_not_edge = (const float*)d_in[3];

    Part* pb = (Part*)d_ws;   // 2048 * 16 B; every slot written by k_fused

    dim3 grid(WW / TS, HH / TS, NB);   // 32 x 32 x 2 = 2048 blocks
    k_fused<<<grid, 256, 0, stream>>>(preds, targets, w_edge, w_not_edge, pb);
    k_final<<<1, 256, 0, stream>>>(pb, (float*)d_out);
}

// Round 8
// 88.242 us; speedup vs baseline: 1.1152x; 1.1016x over previous
//
#include <hip/hip_runtime.h>
#include <stdint.h>

// AAF loss, round 20: revert to validated R16 (best measured: 86.6 us total,
// k_fused ~28-29 us, zero spill) + halo-rotation SIMD balance fix.
// R17-R19 re-pairing lineage abandoned: measured 97-98 us total across three
// variants (spill + trans-pipe pressure); the simple (a,t)-row + in-loop
// capture stage-2 is faster in practice.
// New in R20: halo pixels are owned by a per-block ROTATED thread range
// (((bx+by)&3)*128 .. +100) instead of always tid<100. Wave->SIMD is
// round-robin, so fixed tid<100 put the double-work halo waves of EVERY
// block on SIMDs 0-1; rotation cycles the heavy wave-pair across SIMD
// pairs. Pure re-mapping, no semantic change.
// Structure (validated R16): 32x16 tiles, 512 threads, 3 blocks/CU
// (launch_bounds(512,6)); log2-domain softmax (patch pre-scaled by log2e,
// raw v_exp/v_log, margin 3/ln2, ln2 folded into swe/swn); packed (a2,t2)
// f16 rows stride-20; fully-static stage-2 with in-loop cndmask capture of
// kl@lab / kl@nlab; uint8 TG; per-wave packed counts, unpacked cross-wave.

#define NC 19
#define HH 512
#define WW 512
#define NB 2
#define TSY 32
#define TSX 16
#define HS 18                          // halo grid cols = TSX + 2
#define VS 34                          // halo grid rows = TSY + 2
#define HP (VS * HS)                   // 612
#define ATRS 20                        // row stride words: 80 B, 16B-aligned
#define PS 35                          // 7x5 source patch per class
#define NBLK 1024                      // 32 x 16 x 2 blocks
#define LOG2E 1.4426950408889634f
#define LN2 0.6931471805599453f
#define LOG2EPS -13.287712379549449f   // log2(1e-4)
#define K2F 4.3280851226668906f        // 3/ln2: KLD margin in log2 units
#define K2PAD 4.328125f                // (_Float16)K2F exactly (pad-slot value)

typedef _Float16 f16x2 __attribute__((ext_vector_type(2)));

#if __has_builtin(__builtin_amdgcn_exp2f)
#define EXP2F(x) __builtin_amdgcn_exp2f(x)
#else
#define EXP2F(x) __expf((x) * LN2)
#endif

#if __has_builtin(__builtin_amdgcn_fdot2)
#define FDOT2(a, b, c) __builtin_amdgcn_fdot2((a), (b), (c), false)
#else
#define FDOT2(a, b, c) fmaf((float)(a)[1], (float)(b)[1], fmaf((float)(a)[0], (float)(b)[0], (c)))
#endif

struct Part { float es, ns; unsigned int ec, nc; };

union U32F2 { uint32_t u; f16x2 h; };
__device__ __forceinline__ uint32_t bc_u32(f16x2 v) { U32F2 x; x.h = v; return x.u; }
__device__ __forceinline__ f16x2 bc_h2(uint32_t v) { U32F2 x; x.u = v; return x.h; }
__device__ __forceinline__ float extf(f16x2 v, int h) { return h ? (float)v[1] : (float)v[0]; }

// One pixel's softmax -> packed (a2,t2) row, written as 5 x b128
// (word 4i+0: a-pair 2i, 4i+1: t-pair 2i, 4i+2: a-pair 2i+1, 4i+3: t-pair 2i+1).
// d,l,t are in LOG2 units. KEEP: (d2,l2) pairs kept in registers.
// Returns label (255 = OOB pad).
template <bool KEEP>
__device__ __forceinline__ int pix_compute(const float* __restrict__ patch,
                                           const int* __restrict__ tg,
                                           int y, int x, int y0b, int x0b,
                                           uint32_t* __restrict__ ATrow,
                                           f16x2* Dh, f16x2* Lh) {
    const bool oob = ((unsigned)y >= (unsigned)HH) | ((unsigned)x >= (unsigned)WW);
    if (oob) {
        const _Float16 aP = (_Float16)1e-4f, dP = (_Float16)LOG2EPS;
        const _Float16 tP = (_Float16)((float)aP * (float)dP);
        const uint32_t aPP = bc_u32((f16x2){aP, aP});
        const uint32_t tPP = bc_u32((f16x2){tP, tP});
        const uint32_t aPL = bc_u32((f16x2){aP, (_Float16)0.0f});
        const uint32_t tPL = bc_u32((f16x2){tP, (_Float16)0.0f});
#pragma unroll
        for (int i = 0; i < 5; ++i) {
            uint4 wv;
            wv.x = aPP; wv.y = tPP;
            wv.z = (i < 4) ? aPP : aPL;
            wv.w = (i < 4) ? tPP : tPL;
            *reinterpret_cast<uint4*>(ATrow + 4 * i) = wv;
            if (KEEP) {
                Dh[2 * i] = (f16x2){dP, dP};
                Dh[2 * i + 1] = (i < 4) ? (f16x2){dP, dP} : (f16x2){dP, (_Float16)0.0f};
                Lh[2 * i] = (f16x2){(_Float16)0.0f, (_Float16)0.0f};
                Lh[2 * i + 1] = (f16x2){(_Float16)0.0f, (_Float16)0.0f};
            }
        }
        return 255;
    }

    const int lab = tg[(y << 9) + x];
    const float fy = (float)(y * 63) / 511.0f;
    const float fx = (float)(x * 63) / 511.0f;
    const int y0 = (int)fy, x0 = (int)fx;
    const float wy = fy - (float)y0, wx = fx - (float)x0;
    const int y1 = min(y0 + 1, 63), x1 = min(x0 + 1, 63);
    const float omwy = 1.0f - wy, omwx = 1.0f - wx;
    const float w00 = omwy * omwx, w01 = omwy * wx;
    const float w10 = wy * omwx,   w11 = wy * wx;
    const int o00 = (y0 - y0b) * 5 + (x0 - x0b);
    const int o01 = o00 + (x1 - x0);
    const int o10 = o00 + (y1 - y0) * 5;
    const int o11 = o10 + (x1 - x0);

    // v2 = logits * log2e (patch pre-scaled); no max-subtraction needed.
    float v2[NC], w[NC];
    float s = 0.0f;
#pragma unroll
    for (int c = 0; c < NC; ++c) {
        const float* pc_ = &patch[c * PS];
        const float vv = fmaf(pc_[o00], w00, fmaf(pc_[o01], w01,
                          fmaf(pc_[o10], w10, pc_[o11] * w11)));
        v2[c] = vv;
        const float e = EXP2F(vv);
        w[c] = e;
        s += e;
    }
    const float inv = 1.0f / s;
    const float lns2 = __log2f(s);            // log2 p = v2 - lns2

#pragma unroll
    for (int i = 0; i < 5; ++i) {
        _Float16 av[4], tv[4], dv[4], lv[4];
#pragma unroll
        for (int q = 0; q < 4; ++q) {
            const int c = 4 * i + q;
            _Float16 a16 = (_Float16)0.0f, d16 = (_Float16)0.0f,
                     l16 = (_Float16)0.0f, t16 = (_Float16)0.0f;
            if (c < NC) {
                const float p = w[c] * inv;
                const float la = fmaxf(v2[c] - lns2, LOG2EPS);   // log2(clip p)
                const float aa = fmaxf(p, 1e-4f);
                const float lb = __log2f(fmaxf(1.0f - p, 1e-4f));
                a16 = (_Float16)aa;
                d16 = (_Float16)(la - lb);
                l16 = (_Float16)lb;
                t16 = a16 * d16 + l16;        // v_fma_f16 (contracted)
            }
            av[q] = a16; tv[q] = t16; dv[q] = d16; lv[q] = l16;
        }
        uint4 wv;
        wv.x = bc_u32((f16x2){av[0], av[1]});
        wv.y = bc_u32((f16x2){tv[0], tv[1]});
        wv.z = bc_u32((f16x2){av[2], av[3]});
        wv.w = bc_u32((f16x2){tv[2], tv[3]});
        *reinterpret_cast<uint4*>(ATrow + 4 * i) = wv;   // ds_write_b128
        if (KEEP) {
            Dh[2 * i] = (f16x2){dv[0], dv[1]};
            Dh[2 * i + 1] = (f16x2){dv[2], dv[3]};
            Lh[2 * i] = (f16x2){lv[0], lv[1]};
            Lh[2 * i + 1] = (f16x2){lv[2], lv[3]};
        }
    }
    return lab;
}

__global__ __launch_bounds__(512, 6) void k_fused(const float* __restrict__ preds,
                                                  const int* __restrict__ targets,
                                                  const float* __restrict__ w_edge,
                                                  const float* __restrict__ w_not_edge,
                                                  Part* __restrict__ pb) {
    __shared__ __align__(16) uint32_t AT[HP * ATRS];  // 48,960 B
    __shared__ uint8_t TG[HP];                        // 612 B
    __shared__ float swe[NC], swn[NC];
    __shared__ float patch[NC * PS];                  // 2,660 B
    __shared__ float r_es[8], r_ns[8];
    __shared__ unsigned int r_cnt[8];

    const int tid = threadIdx.x;
    const int bx = blockIdx.x, by = blockIdx.y, n = blockIdx.z;

    if (tid < NC) {
        {
            float a = w_edge[tid * 3 + 0], b = w_edge[tid * 3 + 1], c = w_edge[tid * 3 + 2];
            float m = fmaxf(a, fmaxf(b, c));
            float ea = __expf(a - m), eb = __expf(b - m), ec = __expf(c - m);
            swe[tid] = (ea / (ea + eb + ec)) * LN2;   // ln2: log2-domain rescale
        }
        {
            float a = w_not_edge[tid * 3 + 0], b = w_not_edge[tid * 3 + 1], c = w_not_edge[tid * 3 + 2];
            float m = fmaxf(a, fmaxf(b, c));
            float ea = __expf(a - m), eb = __expf(b - m), ec = __expf(c - m);
            swn[tid] = (ea / (ea + eb + ec)) * LN2;
        }
    }

    const int* tg = targets + (n << 18);
    const float* pbase = preds + (size_t)n * NC * 4096;

    const int ty = tid >> 4, tx = tid & 15;           // ty 0..31
    const int hi = (ty + 1) * HS + (tx + 1);
    const int DOFF[8] = {-HS - 1, -HS, -HS + 1, -1, 1, HS - 1, HS, HS + 1};
    const f16x2 one2 = {(_Float16)1.0f, (_Float16)1.0f};
    const f16x2 k32 = {(_Float16)K2F, (_Float16)K2F};
    const f16x2 z2 = {(_Float16)0.0f, (_Float16)0.0f};

    float e_s = 0.0f, ne_s = 0.0f;
    unsigned int cnt = 0;               // e_c << 16 | ne_c (per-thread max 16|152)

    // ---- stage 0: stage 7x5x19 source patch, pre-scaled by log2e ----
    const int yT = max(by * TSY - 1, 0), xL = max(bx * TSX - 1, 0);
    const int y0b = (yT * 63) / 511, x0b = (xL * 63) / 511;
    for (int t = tid; t < NC * PS; t += 512) {
        const int c = t / PS, r = t - c * PS;
        const int ry = r / 5, rx = r - ry * 5;
        const int sy = min(y0b + ry, 63), sx = min(x0b + rx, 63);
        patch[t] = pbase[c * 4096 + (sy << 6) + sx] * LOG2E;
    }
    __syncthreads();

    // ---- stage 1: halo ring first (temps die), then own pixel ----
    // Halo ownership ROTATES across wave-pairs per block: fixed tid<100 put
    // the double-work waves of every block on SIMDs 0-1 (wave->SIMD is
    // round-robin); rotation spreads them across all 4 SIMDs.
    const int hrot = ((bx + by) & 3) << 7;            // 0,128,256,384
    const int htid = (tid - hrot) & 511;
    if (htid < 100) {
        int i;
        if (htid < 18)      i = htid;                     // top row (row 0)
        else if (htid < 36) i = 33 * HS + (htid - 18);    // bottom row (row 33)
        else if (htid < 68) i = (htid - 35) * HS;         // left col (rows 1..32)
        else                i = (htid - 67) * HS + 17;    // right col (rows 1..32)
        const int hy = i / HS, hx = i - hy * HS;
        TG[i] = (uint8_t)pix_compute<false>(patch, tg, by * TSY + hy - 1, bx * TSX + hx - 1,
                                            y0b, x0b, &AT[i * ATRS], nullptr, nullptr);
    }

    f16x2 Dh[10], Lh[10];
    const int lab = pix_compute<true>(patch, tg, by * TSY + ty, bx * TSX + tx,
                                      y0b, x0b, &AT[hi * ATRS], Dh, Lh);
    TG[hi] = (uint8_t)lab;
    __syncthreads();

    // ---- stage 2 (all kl values in log2 units; margin = K2F) ----
    const bool interior_blk = (bx > 0) & (bx < 31) & (by > 0) & (by < 15);
    const int plab = lab >> 1, hlab = lab & 1;
    float es_h = 0.0f, ns_h = 0.0f;
    unsigned int cnt_h = 0;

    if (interior_blk) {
#pragma unroll
        for (int k = 0; k < 8; ++k) {
            const int np = hi + DOFF[k];
            const int nlab = (int)TG[np];
            const int pn = nlab >> 1, hn = nlab & 1;
            const uint32_t* wbp = &AT[np * ATRS];
            float dot0 = 0.0f, dot1 = 0.0f;
            f16x2 klLw = z2, klNw = z2;
#pragma unroll
            for (int i = 0; i < 5; ++i) {
                const uint4 rd = *reinterpret_cast<const uint4*>(wbp + 4 * i);  // b128
                const int j0 = 2 * i, j1 = 2 * i + 1;
                const f16x2 kl20 = bc_h2(rd.y) - (bc_h2(rd.x) * Dh[j0] + Lh[j0]);
                const f16x2 kl21 = bc_h2(rd.w) - (bc_h2(rd.z) * Dh[j1] + Lh[j1]);
                dot0 = FDOT2(kl20, one2, dot0);
                dot1 = FDOT2(kl21, one2, dot1);
                klLw = (j0 == plab) ? kl20 : klLw;
                klLw = (j1 == plab) ? kl21 : klLw;
                klNw = (j0 == pn) ? kl20 : klNw;
                klNw = (j1 == pn) ? kl21 : klNw;
            }
            const float dot = dot0 + dot1;
            const float klL = extf(klLw, hlab);
            const float klN = extf(klNw, hn);
            const bool df = (lab != nlab);
            const float w = df ? 1.0f : 0.0f;
            es_h = fmaf(w, fmaxf(K2F - klL, 0.0f) + fmaxf(K2F - klN, 0.0f), es_h);
            ns_h += dot - w * (klL + klN);
            cnt_h += df ? ((2u << 16) | (NC - 2)) : NC;
        }
        e_s = fmaf(es_h, swe[lab], e_s);
        ne_s = fmaf(ns_h, swn[lab], ne_s);
        cnt += cnt_h;
    } else if (lab <= NC - 1) {
        // ---- border path: OOB-pad neighbors + reverse-ignore ----
#pragma unroll
        for (int k = 0; k < 8; ++k) {
            const int off = DOFF[k];
            const int rlab = (int)TG[hi - off];
            const int np = hi + off;
            const int nlab = (int)TG[np];
            const int pn = nlab >> 1, hn = nlab & 1;   // pad: pn=127, never hit
            const uint32_t* wbp = &AT[np * ATRS];
            float dot0 = 0.0f, dot1 = 0.0f, ekall = 0.0f;
            f16x2 klLw = z2, klNw = z2;
#pragma unroll
            for (int i = 0; i < 5; ++i) {
                const uint4 rd = *reinterpret_cast<const uint4*>(wbp + 4 * i);
                const int j0 = 2 * i, j1 = 2 * i + 1;
                const f16x2 kl20 = bc_h2(rd.y) - (bc_h2(rd.x) * Dh[j0] + Lh[j0]);
                const f16x2 kl21 = bc_h2(rd.w) - (bc_h2(rd.z) * Dh[j1] + Lh[j1]);
                dot0 = FDOT2(kl20, one2, dot0);
                dot1 = FDOT2(kl21, one2, dot1);
                f16x2 m0 = k32 - kl20, m1 = k32 - kl21;
                m0[0] = m0[0] > (_Float16)0.0f ? m0[0] : (_Float16)0.0f;
                m0[1] = m0[1] > (_Float16)0.0f ? m0[1] : (_Float16)0.0f;
                m1[0] = m1[0] > (_Float16)0.0f ? m1[0] : (_Float16)0.0f;
                m1[1] = m1[1] > (_Float16)0.0f ? m1[1] : (_Float16)0.0f;
                ekall = FDOT2(m0, one2, ekall);
                ekall = FDOT2(m1, one2, ekall);
                klLw = (j0 == plab) ? kl20 : klLw;
                klLw = (j1 == plab) ? kl21 : klLw;
                klNw = (j0 == pn) ? kl20 : klNw;
                klNw = (j1 == pn) ? kl21 : klNw;
            }
            const float dot = dot0 + dot1;
            const float klL = extf(klLw, hlab);
            const float klN = extf(klNw, hn);
            const bool isPad = (nlab == 255);
            const bool df = (lab != nlab) && !isPad;
            const float w = df ? 1.0f : 0.0f;
            const float ek_int = w * (fmaxf(K2F - klL, 0.0f) + fmaxf(K2F - klN, 0.0f));
            const float nk_int = dot - w * (klL + klN);
            const float ek_pad = ekall - K2PAD;      // drop pad-class slot (kl=0 -> K2)
            const float ek_k = isPad ? ek_pad : ek_int;
            const float nk_k = isPad ? 0.0f : nk_int;
            const unsigned int pc = isPad ? NC : (df ? 2u : 0u);
            const bool valid = (rlab <= NC - 1);
            const float vf = valid ? 1.0f : 0.0f;
            es_h = fmaf(vf, ek_k, es_h);
            ns_h = fmaf(vf, nk_k, ns_h);
            cnt_h += valid ? ((pc << 16) | (NC - pc)) : 0u;
        }
        e_s = fmaf(es_h, swe[lab], e_s);
        ne_s = fmaf(ns_h, swn[lab], ne_s);
        cnt += cnt_h;
    }

    // ---- block reduction: packed 32-bit within wave (max 1024<<16|9728),
    //      unpacked across the 8 waves ----
#pragma unroll
    for (int off = 32; off > 0; off >>= 1) {
        e_s  += __shfl_down(e_s, off, 64);
        ne_s += __shfl_down(ne_s, off, 64);
        cnt  += __shfl_down(cnt, off, 64);
    }
    const int wid = tid >> 6, lane = tid & 63;
    if (lane == 0) { r_es[wid] = e_s; r_ns[wid] = ne_s; r_cnt[wid] = cnt; }
    __syncthreads();
    if (tid == 0) {
        float tes = 0.0f, tns = 0.0f;
        unsigned int tec = 0, tnc = 0;
#pragma unroll
        for (int w = 0; w < 8; ++w) {
            tes += r_es[w]; tns += r_ns[w];
            tec += r_cnt[w] >> 16; tnc += r_cnt[w] & 0xFFFFu;
        }
        const int bid = (blockIdx.z * gridDim.y + blockIdx.y) * gridDim.x + blockIdx.x;
        pb[bid].es = tes; pb[bid].ns = tns; pb[bid].ec = tec; pb[bid].nc = tnc;
    }
}

// ---------------- final reduce (1 block) ----------------
__global__ __launch_bounds__(256) void k_final(const Part* __restrict__ pb,
                                               float* __restrict__ out) {
    const int tid = threadIdx.x;
    double es = 0.0, ns = 0.0;
    long long ec = 0, nc = 0;
    for (int i = tid; i < NBLK; i += 256) {
        es += (double)pb[i].es; ns += (double)pb[i].ns;
        ec += (long long)pb[i].ec; nc += (long long)pb[i].nc;
    }
#pragma unroll
    for (int off = 32; off > 0; off >>= 1) {
        es += __shfl_down(es, off, 64);
        ns += __shfl_down(ns, off, 64);
        ec += __shfl_down(ec, off, 64);
        nc += __shfl_down(nc, off, 64);
    }
    __shared__ double ses[4], sns[4];
    __shared__ long long sec[4], snc[4];
    const int wid = tid >> 6, lane = tid & 63;
    if (lane == 0) { ses[wid] = es; sns[wid] = ns; sec[wid] = ec; snc[wid] = nc; }
    __syncthreads();
    if (tid == 0) {
        double tes = 0.0, tns = 0.0;
        long long tec = 0, tnc = 0;
#pragma unroll
        for (int w = 0; w < 4; ++w) { tes += ses[w]; tns += sns[w]; tec += sec[w]; tnc += snc[w]; }
        double ecd = (double)tec; if (ecd < 1.0) ecd = 1.0;
        double ncd = (double)tnc; if (ncd < 1.0) ncd = 1.0;
        out[0] = (float)((tes / ecd) * 0.01 + (tns / ncd) * 0.01);
    }
}

extern "C" void kernel_launch(void* const* d_in, const int* in_sizes, int n_in,
                              void* d_out, int out_size, void* d_ws, size_t ws_size,
                              hipStream_t stream) {
    const float* preds      = (const float*)d_in[0];  // (2,19,64,64) fp32
    const int*   targets    = (const int*)d_in[1];    // (2,512,512) int32
    const float* w_edge     = (const float*)d_in[2];  // (1,1,1,19,1,3) fp32
    const float* w_not_edge = (const float*)d_in[3];

    Part* pb = (Part*)d_ws;   // 1024 * 16 B; every slot written by k_fused

    dim3 grid(WW / TSX, HH / TSY, NB);   // 32 x 16 x 2 = 1024 blocks
    k_fused<<<grid, 512, 0, stream>>>(preds, targets, w_edge, w_not_edge, pb);
    k_final<<<1, 256, 0, stream>>>(pb, (float*)d_out);
}